// Round 1
// baseline (2169.853 us; speedup 1.0000x reference)
//
#include <hip/hip_runtime.h>
#include <math.h>

#define BB 2
#define TT 1024
#define DD 1024
#define HH 16
#define KK 64
#define NBT 2048              // B*T
#define NE  2097152ULL        // B*T*D

constexpr int EPI_FLAT = 0, EPI_SILU = 1, EPI_TANH = 2,
              EPI_HEAD = 3, EPI_BIAS_HEAD = 4, EPI_SIGBIAS_HEAD = 5;

// ---------------- K1: token shift + xxx + hmix = tanh(xxx @ W1) ----------------
__global__ __launch_bounds__(256)
void k1_shift_hmix(const float* __restrict__ x, const float* __restrict__ maa_x,
                   const float* __restrict__ W1, float* __restrict__ dxprev,
                   float* __restrict__ hmix) {
  __shared__ float xs[8 * 1024];
  int row0 = blockIdx.x * 8;
  int tid = threadIdx.x;
  for (int i = tid; i < 8 * 1024; i += 256) {
    int r = i >> 10, d = i & 1023;
    int row = row0 + r;
    int t = row & (TT - 1);
    size_t g = (size_t)row * DD + d;
    float xc = x[g];
    float xl = (t == 0) ? 0.f : x[g - DD];
    float xr = (t == TT - 1) ? 0.f : x[g + DD];
    float dx = 0.5f * (xl + xr) - xc;
    dxprev[g] = dx;
    xs[i] = xc + dx * maa_x[d];
  }
  __syncthreads();
  if (tid < 192) {
    float acc[8] = {0, 0, 0, 0, 0, 0, 0, 0};
    for (int d = 0; d < 1024; ++d) {
      float w = W1[(size_t)d * 192 + tid];
#pragma unroll
      for (int r = 0; r < 8; ++r) acc[r] += xs[r * 1024 + d] * w;
    }
#pragma unroll
    for (int r = 0; r < 8; ++r)
      hmix[(size_t)(row0 + r) * 192 + tid] = tanhf(acc[r]);
  }
}

// ---------------- K2: six mixed inputs x_s = x + dxprev*(maa_s + hmix@W2_s) ----------------
__global__ __launch_bounds__(256)
void k2_mix6(const float* __restrict__ x, const float* __restrict__ dxprev,
             const float* __restrict__ hmix, const float* __restrict__ W2,
             const float* __restrict__ maa_w, const float* __restrict__ maa_k,
             const float* __restrict__ maa_v, const float* __restrict__ maa_r,
             const float* __restrict__ maa_g, const float* __restrict__ maa_a,
             float* __restrict__ x6) {
  __shared__ float hs[8][192];
  int row0 = blockIdx.y * 8;
  int d = blockIdx.x * 256 + threadIdx.x;
  for (int i = threadIdx.x; i < 8 * 192; i += 256)
    hs[i / 192][i % 192] = hmix[(size_t)row0 * 192 + i];
  __syncthreads();
  float xv_[8], dx_[8];
#pragma unroll
  for (int r = 0; r < 8; ++r) {
    xv_[r] = x[(size_t)(row0 + r) * DD + d];
    dx_[r] = dxprev[(size_t)(row0 + r) * DD + d];
  }
  const float* maas[6] = {maa_w, maa_k, maa_v, maa_r, maa_g, maa_a};
#pragma unroll
  for (int s = 0; s < 6; ++s) {
    float acc[8] = {0, 0, 0, 0, 0, 0, 0, 0};
    for (int m = 0; m < 32; ++m) {
      float w = W2[(size_t)(s * 32 + m) * DD + d];
      float h0 = 0.f;
#pragma unroll
      for (int r = 0; r < 8; ++r) { h0 = hs[r][s * 32 + m]; acc[r] += h0 * w; }
    }
    float ma = maas[s][d];
#pragma unroll
    for (int r = 0; r < 8; ++r)
      x6[(size_t)s * NE + (size_t)(row0 + r) * DD + d] = xv_[r] + dx_[r] * (ma + acc[r]);
  }
}

// ---------------- generic tiled SGEMM: C(2048 x N) = A(2048 x Kd) @ B(Kd x N) ----------------
// BM=128, BN=64, BK=16, 256 threads, 8x4 micro-tile
template <int EPI>
__global__ __launch_bounds__(256)
void gemm_k(const float* __restrict__ A, const float* __restrict__ Bm,
            float* __restrict__ C, const float* __restrict__ bias, int N, int Kd) {
  __shared__ float As[16][132];  // As[k][m]
  __shared__ float Bs[16][68];   // Bs[k][n]
  int n0 = blockIdx.x * 64;
  int m0 = blockIdx.y * 128;
  int tid = threadIdx.x;
  int tx = tid & 15;   // 16 col groups * 4
  int ty = tid >> 4;   // 16 row groups * 8
  float acc[8][4] = {};
  for (int k0 = 0; k0 < Kd; k0 += 16) {
#pragma unroll
    for (int i = tid; i < 2048; i += 256) {
      int mm = i >> 4, kk2 = i & 15;
      As[kk2][mm] = A[(size_t)(m0 + mm) * Kd + (k0 + kk2)];
    }
#pragma unroll
    for (int i = tid; i < 1024; i += 256) {
      int kk2 = i >> 6, nn = i & 63;
      Bs[kk2][nn] = Bm[(size_t)(k0 + kk2) * N + (n0 + nn)];
    }
    __syncthreads();
#pragma unroll
    for (int kk2 = 0; kk2 < 16; ++kk2) {
      float a[8], b[4];
#pragma unroll
      for (int r = 0; r < 8; ++r) a[r] = As[kk2][ty * 8 + r];
#pragma unroll
      for (int c = 0; c < 4; ++c) b[c] = Bs[kk2][tx * 4 + c];
#pragma unroll
      for (int r = 0; r < 8; ++r)
#pragma unroll
        for (int c = 0; c < 4; ++c) acc[r][c] += a[r] * b[c];
    }
    __syncthreads();
  }
#pragma unroll
  for (int r = 0; r < 8; ++r) {
    int m = m0 + ty * 8 + r;
    int bb2 = m >> 10, t = m & 1023;
#pragma unroll
    for (int c = 0; c < 4; ++c) {
      int n = n0 + tx * 4 + c;
      float vv = acc[r][c];
      if constexpr (EPI == EPI_SILU) vv = vv / (1.f + expf(-vv));
      if constexpr (EPI == EPI_TANH) vv = tanhf(vv);
      if constexpr (EPI == EPI_BIAS_HEAD) vv += bias[n];
      if constexpr (EPI == EPI_SIGBIAS_HEAD) vv = 1.f / (1.f + expf(-(vv + bias[n])));
      if constexpr (EPI == EPI_FLAT || EPI == EPI_SILU || EPI == EPI_TANH)
        C[(size_t)m * N + n] = vv;
      else
        C[(((size_t)(bb2 * HH + (n >> 6))) * TT + t) * KK + (n & 63)] = vv;
    }
  }
}

// ---------------- K4: kk normalize, kki = kk*iclr, k scale ----------------
__global__ __launch_bounds__(256)
void k4_kfix(float* __restrict__ kbuf, float* __restrict__ kkbuf, float* __restrict__ kkibuf,
             const float* __restrict__ k_k, const float* __restrict__ k_a) {
  int gid = blockIdx.x * 4 + (threadIdx.x >> 6);
  int lane = threadIdx.x & 63;
  size_t base = (size_t)gid * 64 + lane;
  int h = (gid >> 10) & (HH - 1);
  int d = h * 64 + lane;
  float kv = kbuf[base];
  float ic = kkibuf[base];  // iclr was written here
  float kkh = kv * k_k[d];
  float ss = kkh * kkh;
#pragma unroll
  for (int off = 32; off > 0; off >>= 1) ss += __shfl_xor(ss, off);
  float nrm = fmaxf(sqrtf(ss), 1e-12f);
  float kkv = kkh / nrm;
  kkbuf[base] = kkv;
  kkibuf[base] = kkv * ic;
  kbuf[base] = kv * (1.f + (ic - 1.f) * k_a[d]);
}

// ---------------- K5: cumsum of w_h=-exp(w) over T, then clipped csf/csbs ----------------
// csf holds wraw on entry; on exit csf=clip(cs-cs[512]), csbs=clip(cs_b - cs_b[512])
__global__ __launch_bounds__(1024)
void k5_cumsum(float* __restrict__ csf, float* __restrict__ csbs) {
  __shared__ float part[16][64];
  __shared__ float cs512s[64], wh512s[64];
  int bh = blockIdx.x;
  int lane = threadIdx.x & 63;  // k
  int c = threadIdx.x >> 6;     // chunk of 64 timesteps
  size_t base = (size_t)bh * TT * KK + (size_t)c * 64 * KK + lane;
  float p = 0.f;
  for (int i = 0; i < 64; ++i) {
    float wr = csf[base + (size_t)i * KK];
    float wh = -expf(wr);
    csbs[base + (size_t)i * KK] = wh;
    p += wh;
  }
  part[c][lane] = p;
  __syncthreads();
  if (threadIdx.x < 64) {
    float run = 0.f;
#pragma unroll
    for (int cc = 0; cc < 16; ++cc) {
      float tv = part[cc][lane];
      part[cc][lane] = run;
      run += tv;
    }
  }
  __syncthreads();
  float cs = part[c][lane];
  for (int i = 0; i < 64; ++i) {
    float wh = csbs[base + (size_t)i * KK];
    cs += wh;
    csbs[base + (size_t)i * KK] = cs;
    if (c == 8 && i == 0) { cs512s[lane] = cs; wh512s[lane] = wh; }
  }
  __syncthreads();
  float cs512 = cs512s[lane];
  float csb512 = cs512 - wh512s[lane];
  for (int i = 0; i < 64; ++i) {
    size_t g = base + (size_t)i * KK;
    float wr = csf[g];
    float wh = -expf(wr);
    float cc2 = csbs[g];
    csf[g]  = fminf(fmaxf(cc2 - cs512, -60.f), 60.f);
    csbs[g] = fminf(fmaxf((cc2 - wh) - csb512, -60.f), 60.f);
  }
}

// ---------------- attention tile helpers ----------------
__device__ __forceinline__ void tile_mm_nt(const float (*Ra)[65], const float (*Kb)[65],
                                           float (*Sm)[65], int tx, int ty) {
  float sacc[4][4] = {};
  for (int kd = 0; kd < 64; ++kd) {
    float a[4], b[4];
#pragma unroll
    for (int r = 0; r < 4; ++r) a[r] = Ra[ty * 4 + r][kd];
#pragma unroll
    for (int c = 0; c < 4; ++c) b[c] = Kb[tx * 4 + c][kd];
#pragma unroll
    for (int r = 0; r < 4; ++r)
#pragma unroll
      for (int c = 0; c < 4; ++c) sacc[r][c] += a[r] * b[c];
  }
#pragma unroll
  for (int r = 0; r < 4; ++r)
#pragma unroll
    for (int c = 0; c < 4; ++c) Sm[ty * 4 + r][tx * 4 + c] = sacc[r][c];
}

// MODE: 0=all, 1=jj<ig, 2=jj>ig, 3=jj<=ig
template <int MODE>
__device__ __forceinline__ void tile_acc(const float (*Sm)[65], const float (*Vx)[65],
                                         float acc[4][4], int tx, int ty) {
  for (int jj = 0; jj < 64; ++jj) {
    float b[4];
#pragma unroll
    for (int c = 0; c < 4; ++c) b[c] = Vx[jj][tx * 4 + c];
#pragma unroll
    for (int r = 0; r < 4; ++r) {
      int ig = ty * 4 + r;
      bool use = (MODE == 0) || (MODE == 1 && jj < ig) || (MODE == 2 && jj > ig) ||
                 (MODE == 3 && jj <= ig);
      if (use) {
        float s = Sm[ig][jj];
#pragma unroll
        for (int c = 0; c < 4; ++c) acc[r][c] += s * b[c];
      }
    }
  }
}

// ---------------- K6: pass 1 — vf = v - L@v, vb = v - U@v  (L/U strict-tri kk_corr) ----------------
__global__ __launch_bounds__(256)
void k6_pass1(const float* __restrict__ kk, const float* __restrict__ kki,
              const float* __restrict__ v, float* __restrict__ vf, float* __restrict__ vb) {
  __shared__ float Ri[64][65], Kj[64][65], Vj[64][65], Sm[64][65];
  int bh = blockIdx.y, it = blockIdx.x, i0 = it * 64;
  size_t hb = (size_t)bh * TT * KK;
  int tid = threadIdx.x, tx = tid & 15, ty = tid >> 4;
  for (int i = tid; i < 4096; i += 256)
    Ri[i >> 6][i & 63] = kki[hb + (size_t)i0 * 64 + i];
  float af[4][4] = {}, ab[4][4] = {};
  for (int jt = 0; jt < 16; ++jt) {
    int j0 = jt * 64;
    __syncthreads();
    for (int i = tid; i < 4096; i += 256) {
      size_t g = hb + (size_t)j0 * 64 + i;
      Kj[i >> 6][i & 63] = kk[g];
      Vj[i >> 6][i & 63] = v[g];
    }
    __syncthreads();
    tile_mm_nt(Ri, Kj, Sm, tx, ty);
    __syncthreads();
    if (jt < it)      tile_acc<0>(Sm, Vj, af, tx, ty);
    else if (jt > it) tile_acc<0>(Sm, Vj, ab, tx, ty);
    else { tile_acc<1>(Sm, Vj, af, tx, ty); tile_acc<2>(Sm, Vj, ab, tx, ty); }
  }
#pragma unroll
  for (int r = 0; r < 4; ++r) {
    size_t g = hb + (size_t)(i0 + ty * 4 + r) * 64 + tx * 4;
#pragma unroll
    for (int c = 0; c < 4; ++c) {
      float vv = v[g + c];
      vf[g + c] = vv - af[r][c];
      vb[g + c] = vv - ab[r][c];
    }
  }
}

// ---------------- K7: pass 2 — y = tril(Rf Kf^T) vf + triu(Rb Kb^T,1) vb ----------------
__global__ __launch_bounds__(256)
void k7_pass2(const float* __restrict__ rB, const float* __restrict__ kB,
              const float* __restrict__ csf, const float* __restrict__ csbs,
              const float* __restrict__ vf, const float* __restrict__ vb,
              float* __restrict__ y) {
  __shared__ float Rf[64][65], Rb[64][65], Kx[64][65], Vx[64][65], Sm[64][65];
  int bh = blockIdx.y, it = blockIdx.x, i0 = it * 64;
  size_t hb = (size_t)bh * TT * KK;
  int tid = threadIdx.x, tx = tid & 15, ty = tid >> 4;
  for (int i = tid; i < 4096; i += 256) {
    size_t g = hb + (size_t)i0 * 64 + i;
    float rv = rB[g];
    Rf[i >> 6][i & 63] = rv * expf(csf[g]);
    Rb[i >> 6][i & 63] = rv * expf(-csbs[g]);
  }
  float acc[4][4] = {};
  for (int jt = 0; jt < 16; ++jt) {
    int j0 = jt * 64;
    if (jt <= it) {  // forward contribution
      __syncthreads();
      for (int i = tid; i < 4096; i += 256) {
        size_t g = hb + (size_t)j0 * 64 + i;
        Kx[i >> 6][i & 63] = kB[g] * expf(-csf[g]);
        Vx[i >> 6][i & 63] = vf[g];
      }
      __syncthreads();
      tile_mm_nt(Rf, Kx, Sm, tx, ty);
      __syncthreads();
      if (jt < it) tile_acc<0>(Sm, Vx, acc, tx, ty);
      else         tile_acc<3>(Sm, Vx, acc, tx, ty);
    }
    if (jt >= it) {  // backward contribution
      __syncthreads();
      for (int i = tid; i < 4096; i += 256) {
        size_t g = hb + (size_t)j0 * 64 + i;
        Kx[i >> 6][i & 63] = kB[g] * expf(csbs[g]);
        Vx[i >> 6][i & 63] = vb[g];
      }
      __syncthreads();
      tile_mm_nt(Rb, Kx, Sm, tx, ty);
      __syncthreads();
      if (jt > it) tile_acc<0>(Sm, Vx, acc, tx, ty);
      else         tile_acc<2>(Sm, Vx, acc, tx, ty);
    }
  }
#pragma unroll
  for (int r = 0; r < 4; ++r) {
    size_t g = hb + (size_t)(i0 + ty * 4 + r) * 64 + tx * 4;
#pragma unroll
    for (int c = 0; c < 4; ++c) y[g + c] = acc[r][c];
  }
}

// ---------------- K8: GroupNorm(H groups over K) * ln + bias, then * g ----------------
__global__ __launch_bounds__(256)
void k8_gnorm(const float* __restrict__ y, const float* __restrict__ g,
              const float* __restrict__ lnw, const float* __restrict__ lnb,
              float* __restrict__ out) {
  int bt = blockIdx.x;
  int b = bt >> 10, t = bt & 1023;
  int wv = threadIdx.x >> 6, lane = threadIdx.x & 63;
  for (int h = wv; h < HH; h += 4) {
    size_t idx = (((size_t)(b * HH + h)) * TT + t) * KK + lane;
    float v = y[idx];
    float s1 = v, s2 = v * v;
#pragma unroll
    for (int off = 32; off > 0; off >>= 1) {
      s1 += __shfl_xor(s1, off);
      s2 += __shfl_xor(s2, off);
    }
    float mu = s1 * (1.f / 64.f);
    float var = s2 * (1.f / 64.f) - mu * mu;
    float xn = (v - mu) * rsqrtf(var + 6.4e-4f);
    int d = h * 64 + lane;
    float o = xn * lnw[d] + lnb[d];
    out[(size_t)bt * DD + d] = o * g[(size_t)bt * DD + d];
  }
}

extern "C" void kernel_launch(void* const* d_in, const int* in_sizes, int n_in,
                              void* d_out, int out_size, void* d_ws, size_t ws_size,
                              hipStream_t stream) {
  const float* x      = (const float*)d_in[0];
  const float* maa_x  = (const float*)d_in[1];
  const float* maa_w  = (const float*)d_in[2];
  const float* maa_k  = (const float*)d_in[3];
  const float* maa_v  = (const float*)d_in[4];
  const float* maa_r  = (const float*)d_in[5];
  const float* maa_g  = (const float*)d_in[6];
  const float* maa_a  = (const float*)d_in[7];
  const float* w1mix  = (const float*)d_in[8];
  const float* w2mix  = (const float*)d_in[9];
  const float* tdecay = (const float*)d_in[10];
  const float* wdec1  = (const float*)d_in[11];
  const float* wdec2  = (const float*)d_in[12];
  const float* a0     = (const float*)d_in[13];
  const float* a1     = (const float*)d_in[14];
  const float* a2     = (const float*)d_in[15];
  const float* k_k    = (const float*)d_in[16];
  const float* k_a    = (const float*)d_in[17];
  const float* W_r    = (const float*)d_in[18];
  const float* W_k    = (const float*)d_in[19];
  const float* W_v    = (const float*)d_in[20];
  const float* W_g    = (const float*)d_in[21];
  const float* W_o    = (const float*)d_in[22];
  const float* lnw    = (const float*)d_in[23];
  const float* lnb    = (const float*)d_in[24];
  float* out = (float*)d_out;
  float* ws = (float*)d_ws;

  float* dxprev = ws;                        // 2M floats
  float* hmix   = ws + NE;                   // 0.375M
  float* hdec   = ws + NE + 524288;          // 0.125M
  float* ha     = ws + NE + 655360;          // 0.125M
  float* x6     = ws + NE + 1048576;         // 6 x 2M
  float* xw = x6 + 0 * NE;
  float* xk = x6 + 1 * NE;
  float* xv = x6 + 2 * NE;
  float* xr = x6 + 3 * NE;
  float* xg = x6 + 4 * NE;
  float* xa = x6 + 5 * NE;
  float* rbuf   = x6 + 6 * NE;
  float* kbuf   = x6 + 7 * NE;
  float* vbuf   = x6 + 8 * NE;
  float* gbuf   = x6 + 9 * NE;
  float* kkbuf  = x6 + 10 * NE;
  float* kkibuf = x6 + 11 * NE;
  float* csfb   = x6 + 12 * NE;
  float* csbsb  = x6 + 13 * NE;
  // reuse (consumers of these regions have already run by the time they're written):
  float* vfb  = xw;  // pass1 output (xw consumed by decay GEMM)
  float* vbb  = xk;  // pass1 output (xk consumed by k GEMM)
  float* ybuf = xv;  // pass2 output (xv consumed by v GEMM)
  float* gnb  = xr;  // gnorm output (xr consumed by r GEMM)

  dim3 blk(256);
  dim3 gBig(16, 16);  // N/64=16 col tiles, M/128=16 row tiles
  dim3 gSm(1, 16);

  k1_shift_hmix<<<NBT / 8, blk, 0, stream>>>(x, maa_x, w1mix, dxprev, hmix);
  k2_mix6<<<dim3(4, NBT / 8), blk, 0, stream>>>(x, dxprev, hmix, w2mix, maa_w, maa_k,
                                                maa_v, maa_r, maa_g, maa_a, x6);
  gemm_k<EPI_HEAD><<<gBig, blk, 0, stream>>>(xr, W_r, rbuf, nullptr, 1024, 1024);
  gemm_k<EPI_HEAD><<<gBig, blk, 0, stream>>>(xk, W_k, kbuf, nullptr, 1024, 1024);
  gemm_k<EPI_HEAD><<<gBig, blk, 0, stream>>>(xv, W_v, vbuf, nullptr, 1024, 1024);
  gemm_k<EPI_SILU><<<gBig, blk, 0, stream>>>(xg, W_g, gbuf, nullptr, 1024, 1024);
  gemm_k<EPI_TANH><<<gSm, blk, 0, stream>>>(xw, wdec1, hdec, nullptr, 64, 1024);
  gemm_k<EPI_FLAT><<<gSm, blk, 0, stream>>>(xa, a1, ha, nullptr, 64, 1024);
  gemm_k<EPI_BIAS_HEAD><<<gBig, blk, 0, stream>>>(hdec, wdec2, csfb, tdecay, 1024, 64);
  gemm_k<EPI_SIGBIAS_HEAD><<<gBig, blk, 0, stream>>>(ha, a2, kkibuf, a0, 1024, 64);
  k4_kfix<<<(BB * HH * TT) / 4, blk, 0, stream>>>(kbuf, kkbuf, kkibuf, k_k, k_a);
  k5_cumsum<<<BB * HH, 1024, 0, stream>>>(csfb, csbsb);
  k6_pass1<<<dim3(16, BB * HH), blk, 0, stream>>>(kkbuf, kkibuf, vbuf, vfb, vbb);
  k7_pass2<<<dim3(16, BB * HH), blk, 0, stream>>>(rbuf, kbuf, csfb, csbsb, vfb, vbb, ybuf);
  k8_gnorm<<<NBT, blk, 0, stream>>>(ybuf, gbuf, lnw, lnb, gnb);
  gemm_k<EPI_FLAT><<<gBig, blk, 0, stream>>>(gnb, W_o, out, nullptr, 1024, 1024);
}

// Round 2
// 833.174 us; speedup vs baseline: 2.6043x; 2.6043x over previous
//
#include <hip/hip_runtime.h>
#include <math.h>

#define BB 2
#define TT 1024
#define DD 1024
#define HH 16
#define KK 64
#define NBT 2048              // B*T
#define NE  2097152ULL        // B*T*D

typedef unsigned short u16;
typedef __attribute__((ext_vector_type(8))) short short8;   // 8 bf16 (4 VGPR)
typedef __attribute__((ext_vector_type(4))) short short4v;  // 4 bf16 (8B)
typedef __attribute__((ext_vector_type(4))) float f32x4;

__device__ __forceinline__ float bf2f(u16 u) {
  union { unsigned int i; float f; } v; v.i = ((unsigned int)u) << 16; return v.f;
}
__device__ __forceinline__ u16 f2bf(float x) {
  union { float f; unsigned int u; } v; v.f = x;
  unsigned int r = v.u + 0x7fffu + ((v.u >> 16) & 1u);
  return (u16)(r >> 16);
}
__device__ __forceinline__ f32x4 MFMA(short8 a, short8 b, f32x4 c) {
  return __builtin_amdgcn_mfma_f32_16x16x32_bf16(a, b, c, 0, 0, 0);
}
// XOR swizzle for [64 rows][128B] LDS tiles (G4: 128B rows are 32-way conflict)
__device__ __forceinline__ int swzb(int row, int kbyte) {
  return row * 128 + (kbyte ^ ((row & 7) << 4));
}
__device__ __forceinline__ void gload16(const void* g, void* l) {
  __builtin_amdgcn_global_load_lds((const __attribute__((address_space(1))) void*)g,
                                   (__attribute__((address_space(3))) void*)l, 16, 0, 0);
}

constexpr int EPI_FLAT = 0, EPI_TANH = 2, EPI_BIAS_HEAD = 4, EPI_SIGBIAS_HEAD = 5;
constexpr int EPI_OUT = 0, EPI_GSILU = 1, EPI_HEADB = 2, EPI_VTB = 3;

// ---------------- K1: token shift + xxx + hmix = tanh(xxx @ W1) ----------------
__global__ __launch_bounds__(256)
void k1_shift_hmix(const float* __restrict__ x, const float* __restrict__ maa_x,
                   const float* __restrict__ W1, float* __restrict__ dxprev,
                   float* __restrict__ hmix) {
  __shared__ float xs[8 * 1024];
  int row0 = blockIdx.x * 8;
  int tid = threadIdx.x;
  for (int i = tid; i < 8 * 1024; i += 256) {
    int r = i >> 10, d = i & 1023;
    int row = row0 + r;
    int t = row & (TT - 1);
    size_t g = (size_t)row * DD + d;
    float xc = x[g];
    float xl = (t == 0) ? 0.f : x[g - DD];
    float xr = (t == TT - 1) ? 0.f : x[g + DD];
    float dx = 0.5f * (xl + xr) - xc;
    dxprev[g] = dx;
    xs[i] = xc + dx * maa_x[d];
  }
  __syncthreads();
  if (tid < 192) {
    float acc[8] = {0, 0, 0, 0, 0, 0, 0, 0};
    for (int d = 0; d < 1024; ++d) {
      float w = W1[(size_t)d * 192 + tid];
#pragma unroll
      for (int r = 0; r < 8; ++r) acc[r] += xs[r * 1024 + d] * w;
    }
#pragma unroll
    for (int r = 0; r < 8; ++r)
      hmix[(size_t)(row0 + r) * 192 + tid] = tanhf(acc[r]);
  }
}

// ---------------- K2: six mixed inputs; w,a fp32; k,v,r,g bf16 ----------------
__global__ __launch_bounds__(256)
void k2_mix6(const float* __restrict__ x, const float* __restrict__ dxprev,
             const float* __restrict__ hmix, const float* __restrict__ W2,
             const float* __restrict__ maa_w, const float* __restrict__ maa_k,
             const float* __restrict__ maa_v, const float* __restrict__ maa_r,
             const float* __restrict__ maa_g, const float* __restrict__ maa_a,
             float* __restrict__ xw, float* __restrict__ xa,
             u16* __restrict__ xk_b, u16* __restrict__ xv_b,
             u16* __restrict__ xr_b, u16* __restrict__ xg_b) {
  __shared__ float hs[8][192];
  int row0 = blockIdx.y * 8;
  int d = blockIdx.x * 256 + threadIdx.x;
  for (int i = threadIdx.x; i < 8 * 192; i += 256)
    hs[i / 192][i % 192] = hmix[(size_t)row0 * 192 + i];
  __syncthreads();
  float xv_[8], dx_[8];
#pragma unroll
  for (int r = 0; r < 8; ++r) {
    xv_[r] = x[(size_t)(row0 + r) * DD + d];
    dx_[r] = dxprev[(size_t)(row0 + r) * DD + d];
  }
  const float* maas[6] = {maa_w, maa_k, maa_v, maa_r, maa_g, maa_a};
#pragma unroll
  for (int s = 0; s < 6; ++s) {
    float acc[8] = {0, 0, 0, 0, 0, 0, 0, 0};
    for (int m = 0; m < 32; ++m) {
      float w = W2[(size_t)(s * 32 + m) * DD + d];
#pragma unroll
      for (int r = 0; r < 8; ++r) acc[r] += hs[r][s * 32 + m] * w;
    }
    float ma = maas[s][d];
#pragma unroll
    for (int r = 0; r < 8; ++r) {
      size_t idx = (size_t)(row0 + r) * DD + d;
      float val = xv_[r] + dx_[r] * (ma + acc[r]);
      if (s == 0) xw[idx] = val;
      else if (s == 5) xa[idx] = val;
      else if (s == 1) xk_b[idx] = f2bf(val);
      else if (s == 2) xv_b[idx] = f2bf(val);
      else if (s == 3) xr_b[idx] = f2bf(val);
      else xg_b[idx] = f2bf(val);
    }
  }
}

// ---------------- weight transpose fp32[k][n] -> bf16 [n][k] ----------------
__global__ __launch_bounds__(256)
void wtrans(const float* __restrict__ W, u16* __restrict__ Wt) {
  __shared__ float tl[64][65];
  int k0 = blockIdx.x * 64, n0 = blockIdx.y * 64;
  int tid = threadIdx.x;
  int r = tid >> 2, c0 = (tid & 3) * 16;
#pragma unroll
  for (int j = 0; j < 16; j += 4) {
    f32x4 v = *(const f32x4*)(W + (size_t)(k0 + r) * 1024 + n0 + c0 + j);
    tl[r][c0 + j + 0] = v[0]; tl[r][c0 + j + 1] = v[1];
    tl[r][c0 + j + 2] = v[2]; tl[r][c0 + j + 3] = v[3];
  }
  __syncthreads();
  u16 o[16];
#pragma unroll
  for (int j = 0; j < 16; ++j) o[j] = f2bf(tl[c0 + j][r]);
  *(short8*)(Wt + (size_t)(n0 + r) * 1024 + k0 + c0) = *(short8*)(o);
  *(short8*)(Wt + (size_t)(n0 + r) * 1024 + k0 + c0 + 8) = *(short8*)(o + 8);
}

// ---------------- bf16 MFMA GEMM: C(2048 x 1024) = A(2048 x 1024) @ Bt^T ----------------
// BM=128, BN=64, BK=32; 4 waves as 2x2; wave tile 64x32 (frags 4x2)
template <int EPI>
__global__ __launch_bounds__(256)
void gemm_bf(const u16* __restrict__ A, const u16* __restrict__ Bt,
             void* __restrict__ Cv) {
  __shared__ u16 As[128 * 32];
  __shared__ u16 Bs[64 * 32];
  int m0 = blockIdx.y * 128, n0 = blockIdx.x * 64;
  int tid = threadIdx.x, w = tid >> 6, lane = tid & 63;
  int mq = w >> 1, nq = w & 1;
  f32x4 acc[4][2];
#pragma unroll
  for (int i = 0; i < 4; ++i)
#pragma unroll
    for (int j = 0; j < 2; ++j) acc[i][j] = {0.f, 0.f, 0.f, 0.f};
  for (int k0 = 0; k0 < 1024; k0 += 32) {
#pragma unroll
    for (int c2 = 0; c2 < 2; ++c2) {
      int ch = w * 2 + c2;
      int row = ch * 16 + (lane >> 2);
      gload16(A + (size_t)(m0 + row) * 1024 + k0 + (lane & 3) * 8, As + ch * 512);
    }
    {
      int row = w * 16 + (lane >> 2);
      gload16(Bt + (size_t)(n0 + row) * 1024 + k0 + (lane & 3) * 8, Bs + w * 512);
    }
    __syncthreads();
    short8 a[4], b[2];
#pragma unroll
    for (int mf = 0; mf < 4; ++mf)
      a[mf] = *(const short8*)(As + (mq * 64 + mf * 16 + (lane & 15)) * 32 + (lane >> 4) * 8);
#pragma unroll
    for (int nf = 0; nf < 2; ++nf)
      b[nf] = *(const short8*)(Bs + (nq * 32 + nf * 16 + (lane & 15)) * 32 + (lane >> 4) * 8);
#pragma unroll
    for (int mf = 0; mf < 4; ++mf)
#pragma unroll
      for (int nf = 0; nf < 2; ++nf) acc[mf][nf] = MFMA(a[mf], b[nf], acc[mf][nf]);
    __syncthreads();
  }
#pragma unroll
  for (int mf = 0; mf < 4; ++mf) {
#pragma unroll
    for (int nf = 0; nf < 2; ++nf) {
      int mb = m0 + mq * 64 + mf * 16 + (lane >> 4) * 4;
      int n = n0 + nq * 32 + nf * 16 + (lane & 15);
      if constexpr (EPI == EPI_VTB) {
        u16 o[4];
#pragma unroll
        for (int r = 0; r < 4; ++r) o[r] = f2bf(acc[mf][nf][r]);
        int b2 = mb >> 10, t = mb & 1023;
        u16* C = (u16*)Cv;
        *(short4v*)(C + (((size_t)(b2 * HH + (n >> 6))) * KK + (n & 63)) * TT + t) = *(short4v*)o;
      } else {
#pragma unroll
        for (int r = 0; r < 4; ++r) {
          int m = mb + r;
          float v = acc[mf][nf][r];
          if constexpr (EPI == EPI_OUT) {
            ((float*)Cv)[(size_t)m * 1024 + n] = v;
          } else if constexpr (EPI == EPI_GSILU) {
            ((float*)Cv)[(size_t)m * 1024 + n] = v / (1.f + __expf(-v));
          } else {  // EPI_HEADB: bf16 head layout [b*H+h][t][k]
            int b2 = m >> 10, t = m & 1023;
            ((u16*)Cv)[(((size_t)(b2 * HH + (n >> 6))) * TT + t) * KK + (n & 63)] = f2bf(v);
          }
        }
      }
    }
  }
}

// ---------------- legacy fp32 GEMM (w/a LoRA paths) ----------------
template <int EPI>
__global__ __launch_bounds__(256)
void gemm_k(const float* __restrict__ A, const float* __restrict__ Bm,
            float* __restrict__ C, const float* __restrict__ bias, int N, int Kd) {
  __shared__ float As[16][132];
  __shared__ float Bs[16][68];
  int n0 = blockIdx.x * 64;
  int m0 = blockIdx.y * 128;
  int tid = threadIdx.x;
  int tx = tid & 15;
  int ty = tid >> 4;
  float acc[8][4] = {};
  for (int k0 = 0; k0 < Kd; k0 += 16) {
#pragma unroll
    for (int i = tid; i < 2048; i += 256) {
      int mm = i >> 4, kk2 = i & 15;
      As[kk2][mm] = A[(size_t)(m0 + mm) * Kd + (k0 + kk2)];
    }
#pragma unroll
    for (int i = tid; i < 1024; i += 256) {
      int kk2 = i >> 6, nn = i & 63;
      Bs[kk2][nn] = Bm[(size_t)(k0 + kk2) * N + (n0 + nn)];
    }
    __syncthreads();
#pragma unroll
    for (int kk2 = 0; kk2 < 16; ++kk2) {
      float a[8], b[4];
#pragma unroll
      for (int r = 0; r < 8; ++r) a[r] = As[kk2][ty * 8 + r];
#pragma unroll
      for (int c = 0; c < 4; ++c) b[c] = Bs[kk2][tx * 4 + c];
#pragma unroll
      for (int r = 0; r < 8; ++r)
#pragma unroll
        for (int c = 0; c < 4; ++c) acc[r][c] += a[r] * b[c];
    }
    __syncthreads();
  }
#pragma unroll
  for (int r = 0; r < 8; ++r) {
    int m = m0 + ty * 8 + r;
    int bb2 = m >> 10, t = m & 1023;
#pragma unroll
    for (int c = 0; c < 4; ++c) {
      int n = n0 + tx * 4 + c;
      float vv = acc[r][c];
      if constexpr (EPI == EPI_TANH) vv = tanhf(vv);
      if constexpr (EPI == EPI_BIAS_HEAD) vv += bias[n];
      if constexpr (EPI == EPI_SIGBIAS_HEAD) vv = 1.f / (1.f + expf(-(vv + bias[n])));
      if constexpr (EPI == EPI_FLAT || EPI == EPI_TANH)
        C[(size_t)m * N + n] = vv;
      else
        C[(((size_t)(bb2 * HH + (n >> 6))) * TT + t) * KK + (n & 63)] = vv;
    }
  }
}

// ---------------- K4: kk normalize, kki, k scale (bf16 in/out) ----------------
__global__ __launch_bounds__(256)
void k4_kfix(u16* __restrict__ kbuf, u16* __restrict__ kkbuf, u16* __restrict__ kkibuf,
             const float* __restrict__ iclr, const float* __restrict__ k_k,
             const float* __restrict__ k_a) {
  int gid = blockIdx.x * 4 + (threadIdx.x >> 6);
  int lane = threadIdx.x & 63;
  size_t base = (size_t)gid * 64 + lane;
  int h = (gid >> 10) & (HH - 1);
  int d = h * 64 + lane;
  float kv = bf2f(kbuf[base]);
  float ic = iclr[base];
  float kkh = kv * k_k[d];
  float ss = kkh * kkh;
#pragma unroll
  for (int off = 32; off > 0; off >>= 1) ss += __shfl_xor(ss, off);
  float nrm = fmaxf(sqrtf(ss), 1e-12f);
  float kkv = kkh / nrm;
  kkbuf[base] = f2bf(kkv);
  kkibuf[base] = f2bf(kkv * ic);
  kbuf[base] = f2bf(kv * (1.f + (ic - 1.f) * k_a[d]));
}

// ---------------- K5: cumsum + clipped csf/csbs (fp32, unchanged) ----------------
__global__ __launch_bounds__(1024)
void k5_cumsum(float* __restrict__ csf, float* __restrict__ csbs) {
  __shared__ float part[16][64];
  __shared__ float cs512s[64], wh512s[64];
  int bh = blockIdx.x;
  int lane = threadIdx.x & 63;
  int c = threadIdx.x >> 6;
  size_t base = (size_t)bh * TT * KK + (size_t)c * 64 * KK + lane;
  float p = 0.f;
  for (int i = 0; i < 64; ++i) {
    float wr = csf[base + (size_t)i * KK];
    float wh = -expf(wr);
    csbs[base + (size_t)i * KK] = wh;
    p += wh;
  }
  part[c][lane] = p;
  __syncthreads();
  if (threadIdx.x < 64) {
    float run = 0.f;
#pragma unroll
    for (int cc = 0; cc < 16; ++cc) {
      float tv = part[cc][lane];
      part[cc][lane] = run;
      run += tv;
    }
  }
  __syncthreads();
  float cs = part[c][lane];
  for (int i = 0; i < 64; ++i) {
    float wh = csbs[base + (size_t)i * KK];
    cs += wh;
    csbs[base + (size_t)i * KK] = cs;
    if (c == 8 && i == 0) { cs512s[lane] = cs; wh512s[lane] = wh; }
  }
  __syncthreads();
  float cs512 = cs512s[lane];
  float csb512 = cs512 - wh512s[lane];
  for (int i = 0; i < 64; ++i) {
    size_t g = base + (size_t)i * KK;
    float wr = csf[g];
    float wh = -expf(wr);
    float cc2 = csbs[g];
    csf[g] = fminf(fmaxf(cc2 - cs512, -60.f), 60.f);
    csbs[g] = fminf(fmaxf((cc2 - wh) - csb512, -60.f), 60.f);
  }
}

// ---------------- attention tile helpers (bf16 MFMA) ----------------
__device__ __forceinline__ void stage_copy(const u16* src, int rstride, u16* lds) {
  int tid = threadIdx.x;
#pragma unroll
  for (int c = 0; c < 2; ++c) {
    int ch = tid + c * 256;
    int row = ch >> 3, slot = ch & 7;
    short8 v = *(const short8*)(src + (size_t)row * rstride + slot * 8);
    *(short8*)((char*)lds + swzb(row, slot * 16)) = v;
  }
}
template <int PLUS>  // 0: k*exp(-cs); 1: k*exp(+cs)
__device__ __forceinline__ void stage_kexp(const u16* ksrc, const float* csrc, u16* lds) {
  int tid = threadIdx.x;
#pragma unroll
  for (int c = 0; c < 2; ++c) {
    int ch = tid + c * 256;
    int row = ch >> 3, slot = ch & 7;
    short8 kv = *(const short8*)(ksrc + (size_t)row * 64 + slot * 8);
    const float* cp = csrc + (size_t)row * 64 + slot * 8;
    u16 o[8];
#pragma unroll
    for (int j = 0; j < 8; ++j) {
      float cs = cp[j];
      o[j] = f2bf(bf2f((u16)kv[j]) * __expf(PLUS ? cs : -cs));
    }
    *(short8*)((char*)lds + swzb(row, slot * 16)) = *(short8*)o;
  }
}
// MASK: 0 none, 1 keep jl<il, 2 keep jl>il, 3 keep jl<=il
template <int MASK>
__device__ __forceinline__ void store_S(const f32x4 s[4], u16* St, int lane, int w) {
  int ig0 = w * 16 + (lane >> 4) * 4;
#pragma unroll
  for (int jf = 0; jf < 4; ++jf) {
    int jl = jf * 16 + (lane & 15);
#pragma unroll
    for (int r = 0; r < 4; ++r) {
      int il = ig0 + r;
      float v = s[jf][r];
      if (MASK == 1 && !(jl < il)) v = 0.f;
      if (MASK == 2 && !(jl > il)) v = 0.f;
      if (MASK == 3 && !(jl <= il)) v = 0.f;
      *(u16*)((char*)St + swzb(il, jl * 2)) = f2bf(v);
    }
  }
}
__device__ __forceinline__ void smm(const short8 afr[2], const u16* Kt, f32x4 s[4], int lane) {
#pragma unroll
  for (int jf = 0; jf < 4; ++jf) {
    f32x4 z = {0.f, 0.f, 0.f, 0.f};
#pragma unroll
    for (int ks = 0; ks < 2; ++ks) {
      short8 kb = *(const short8*)((const char*)Kt + swzb(jf * 16 + (lane & 15), ks * 64 + (lane >> 4) * 16));
      z = MFMA(afr[ks], kb, z);
    }
    s[jf] = z;
  }
}
__device__ __forceinline__ void pv(const u16* St, const u16* Vt, f32x4 acc[4], int lane, int w) {
#pragma unroll
  for (int ks = 0; ks < 2; ++ks) {
    short8 a = *(const short8*)((const char*)St + swzb(w * 16 + (lane & 15), ks * 64 + (lane >> 4) * 16));
#pragma unroll
    for (int cf = 0; cf < 4; ++cf) {
      short8 b = *(const short8*)((const char*)Vt + swzb(cf * 16 + (lane & 15), ks * 64 + (lane >> 4) * 16));
      acc[cf] = MFMA(a, b, acc[cf]);
    }
  }
}

// ---------------- K6: pass 1 — vfT = vT - (L@v)^T, vbT = vT - (U@v)^T ----------------
__global__ __launch_bounds__(256)
void k6_pass1(const u16* __restrict__ kk, const u16* __restrict__ kki,
              const u16* __restrict__ vT, u16* __restrict__ vfT, u16* __restrict__ vbT) {
  __shared__ u16 Kt[4096], Vt[4096], St[4096];
  int bh = blockIdx.y, it = blockIdx.x, i0 = it * 64;
  size_t hb = (size_t)bh * 65536;
  int tid = threadIdx.x, w = tid >> 6, lane = tid & 63;
  int iw = i0 + w * 16;
  short8 afr[2];
  {
    int row = iw + (lane & 15);
#pragma unroll
    for (int s = 0; s < 2; ++s)
      afr[s] = *(const short8*)(kki + hb + (size_t)row * 64 + s * 32 + (lane >> 4) * 8);
  }
  f32x4 af[4], ab[4];
#pragma unroll
  for (int c = 0; c < 4; ++c) { af[c] = {0.f, 0.f, 0.f, 0.f}; ab[c] = {0.f, 0.f, 0.f, 0.f}; }
  for (int jt = 0; jt < 16; ++jt) {
    int j0 = jt * 64;
    __syncthreads();
    stage_copy(kk + hb + (size_t)j0 * 64, 64, Kt);
    stage_copy(vT + hb + j0, 1024, Vt);
    __syncthreads();
    f32x4 s[4];
    smm(afr, Kt, s, lane);
    if (jt == it) {
      store_S<1>(s, St, lane, w);
      __syncthreads();
      pv(St, Vt, af, lane, w);
      __syncthreads();
      store_S<2>(s, St, lane, w);
      __syncthreads();
      pv(St, Vt, ab, lane, w);
    } else {
      store_S<0>(s, St, lane, w);
      __syncthreads();
      if (jt < it) pv(St, Vt, af, lane, w);
      else pv(St, Vt, ab, lane, w);
    }
  }
#pragma unroll
  for (int cf = 0; cf < 4; ++cf) {
    int c = cf * 16 + (lane & 15);
    int i = iw + (lane >> 4) * 4;
    size_t g = hb + (size_t)c * 1024 + i;
    short4v vv = *(const short4v*)(vT + g);
    u16 o1[4], o2[4];
#pragma unroll
    for (int r = 0; r < 4; ++r) {
      float v0 = bf2f((u16)vv[r]);
      o1[r] = f2bf(v0 - af[cf][r]);
      o2[r] = f2bf(v0 - ab[cf][r]);
    }
    *(short4v*)(vfT + g) = *(short4v*)o1;
    *(short4v*)(vbT + g) = *(short4v*)o2;
  }
}

// ---------------- K7: pass 2 — y = tril(Rf Kf^T) vf + triu(Rb Kb^T,1) vb ----------------
__global__ __launch_bounds__(256)
void k7_pass2(const u16* __restrict__ rb, const u16* __restrict__ kb,
              const float* __restrict__ csf, const float* __restrict__ csbs,
              const u16* __restrict__ vfT, const u16* __restrict__ vbT,
              float* __restrict__ y) {
  __shared__ u16 Kt[4096], Vt[4096], St[4096];
  int bh = blockIdx.y, it = blockIdx.x, i0 = it * 64;
  size_t hb = (size_t)bh * 65536;
  int tid = threadIdx.x, w = tid >> 6, lane = tid & 63;
  int iw = i0 + w * 16;
  short8 rf[2], rbk[2];
  {
    int row = iw + (lane & 15);
#pragma unroll
    for (int s = 0; s < 2; ++s) {
      int k = s * 32 + (lane >> 4) * 8;
      const u16* rp = rb + hb + (size_t)row * 64 + k;
      const float* cf = csf + hb + (size_t)row * 64 + k;
      const float* cb = csbs + hb + (size_t)row * 64 + k;
      u16 a[8], b[8];
#pragma unroll
      for (int j = 0; j < 8; ++j) {
        float rv = bf2f(rp[j]);
        a[j] = f2bf(rv * __expf(cf[j]));
        b[j] = f2bf(rv * __expf(-cb[j]));
      }
      rf[s] = *(short8*)a;
      rbk[s] = *(short8*)b;
    }
  }
  f32x4 acc[4];
#pragma unroll
  for (int c = 0; c < 4; ++c) acc[c] = {0.f, 0.f, 0.f, 0.f};
  for (int jt = 0; jt < 16; ++jt) {
    int j0 = jt * 64;
    if (jt <= it) {  // forward
      __syncthreads();
      stage_kexp<0>(kb + hb + (size_t)j0 * 64, csf + hb + (size_t)j0 * 64, Kt);
      stage_copy(vfT + hb + j0, 1024, Vt);
      __syncthreads();
      f32x4 s[4];
      smm(rf, Kt, s, lane);
      if (jt == it) store_S<3>(s, St, lane, w);
      else store_S<0>(s, St, lane, w);
      __syncthreads();
      pv(St, Vt, acc, lane, w);
    }
    if (jt >= it) {  // backward
      __syncthreads();
      stage_kexp<1>(kb + hb + (size_t)j0 * 64, csbs + hb + (size_t)j0 * 64, Kt);
      stage_copy(vbT + hb + j0, 1024, Vt);
      __syncthreads();
      f32x4 s[4];
      smm(rbk, Kt, s, lane);
      if (jt == it) store_S<2>(s, St, lane, w);
      else store_S<0>(s, St, lane, w);
      __syncthreads();
      pv(St, Vt, acc, lane, w);
    }
  }
#pragma unroll
  for (int cf = 0; cf < 4; ++cf) {
    int c = cf * 16 + (lane & 15);
#pragma unroll
    for (int r = 0; r < 4; ++r) {
      int i = iw + (lane >> 4) * 4 + r;
      y[hb + (size_t)i * 64 + c] = acc[cf][r];
    }
  }
}

// ---------------- K8: GroupNorm * ln + bias, * g -> bf16 ----------------
__global__ __launch_bounds__(256)
void k8_gnorm(const float* __restrict__ y, const float* __restrict__ g,
              const float* __restrict__ lnw, const float* __restrict__ lnb,
              u16* __restrict__ outb) {
  int bt = blockIdx.x;
  int b = bt >> 10, t = bt & 1023;
  int wv = threadIdx.x >> 6, lane = threadIdx.x & 63;
  for (int h = wv; h < HH; h += 4) {
    size_t idx = (((size_t)(b * HH + h)) * TT + t) * KK + lane;
    float v = y[idx];
    float s1 = v, s2 = v * v;
#pragma unroll
    for (int off = 32; off > 0; off >>= 1) {
      s1 += __shfl_xor(s1, off);
      s2 += __shfl_xor(s2, off);
    }
    float mu = s1 * (1.f / 64.f);
    float var = s2 * (1.f / 64.f) - mu * mu;
    float xn = (v - mu) * rsqrtf(var + 6.4e-4f);
    int d = h * 64 + lane;
    float o = xn * lnw[d] + lnb[d];
    outb[(size_t)bt * DD + d] = f2bf(o * g[(size_t)bt * DD + d]);
  }
}

extern "C" void kernel_launch(void* const* d_in, const int* in_sizes, int n_in,
                              void* d_out, int out_size, void* d_ws, size_t ws_size,
                              hipStream_t stream) {
  const float* x      = (const float*)d_in[0];
  const float* maa_x  = (const float*)d_in[1];
  const float* maa_w  = (const float*)d_in[2];
  const float* maa_k  = (const float*)d_in[3];
  const float* maa_v  = (const float*)d_in[4];
  const float* maa_r  = (const float*)d_in[5];
  const float* maa_g  = (const float*)d_in[6];
  const float* maa_a  = (const float*)d_in[7];
  const float* w1mix  = (const float*)d_in[8];
  const float* w2mix  = (const float*)d_in[9];
  const float* tdecay = (const float*)d_in[10];
  const float* wdec1  = (const float*)d_in[11];
  const float* wdec2  = (const float*)d_in[12];
  const float* a0     = (const float*)d_in[13];
  const float* a1     = (const float*)d_in[14];
  const float* a2     = (const float*)d_in[15];
  const float* k_k    = (const float*)d_in[16];
  const float* k_a    = (const float*)d_in[17];
  const float* W_r    = (const float*)d_in[18];
  const float* W_k    = (const float*)d_in[19];
  const float* W_v    = (const float*)d_in[20];
  const float* W_g    = (const float*)d_in[21];
  const float* W_o    = (const float*)d_in[22];
  const float* lnw    = (const float*)d_in[23];
  const float* lnb    = (const float*)d_in[24];
  float* out = (float*)d_out;

  const size_t NEf = NE;
  float* F = (float*)d_ws;
  float* dxprev = F;               // NE (reused as ybuf)
  float* ybuf   = F;
  float* xw     = F + 1 * NEf;
  float* xa     = F + 2 * NEf;
  float* csfb   = F + 3 * NEf;
  float* csbsb  = F + 4 * NEf;
  float* iclr   = F + 5 * NEf;
  float* gbuf   = F + 6 * NEf;
  float* hmix   = F + 7 * NEf;                 // 393216
  float* hdec   = F + 7 * NEf + 524288;        // 131072
  float* ha     = F + 7 * NEf + 786432;        // 131072
  u16* U = (u16*)(F + 8 * NEf);
  u16* xr_b = U + 0 * NEf;
  u16* xk_b = U + 1 * NEf;
  u16* xv_b = U + 2 * NEf;
  u16* xg_b = U + 3 * NEf;
  u16* rbuf = U + 4 * NEf;
  u16* kbuf = U + 5 * NEf;
  u16* vT   = U + 6 * NEf;
  u16* kkb  = U + 7 * NEf;
  u16* kkib = U + 8 * NEf;
  u16* vfT  = U + 9 * NEf;
  u16* vbT  = U + 10 * NEf;
  u16* gnb  = U + 11 * NEf;
  u16* WtR  = U + 12 * NEf;
  u16* WtK  = U + 12 * NEf + 1048576;
  u16* WtV  = U + 12 * NEf + 2097152;
  u16* WtG  = U + 12 * NEf + 3145728;
  u16* WtO  = U + 12 * NEf + 4194304;

  dim3 blk(256);
  dim3 gT(16, 16);
  wtrans<<<gT, blk, 0, stream>>>(W_r, WtR);
  wtrans<<<gT, blk, 0, stream>>>(W_k, WtK);
  wtrans<<<gT, blk, 0, stream>>>(W_v, WtV);
  wtrans<<<gT, blk, 0, stream>>>(W_g, WtG);
  wtrans<<<gT, blk, 0, stream>>>(W_o, WtO);

  k1_shift_hmix<<<NBT / 8, blk, 0, stream>>>(x, maa_x, w1mix, dxprev, hmix);
  k2_mix6<<<dim3(4, NBT / 8), blk, 0, stream>>>(x, dxprev, hmix, w2mix, maa_w, maa_k,
                                                maa_v, maa_r, maa_g, maa_a,
                                                xw, xa, xk_b, xv_b, xr_b, xg_b);

  gemm_bf<EPI_HEADB><<<gT, blk, 0, stream>>>(xr_b, WtR, rbuf);
  gemm_bf<EPI_HEADB><<<gT, blk, 0, stream>>>(xk_b, WtK, kbuf);
  gemm_bf<EPI_VTB><<<gT, blk, 0, stream>>>(xv_b, WtV, vT);
  gemm_bf<EPI_GSILU><<<gT, blk, 0, stream>>>(xg_b, WtG, gbuf);

  gemm_k<EPI_TANH><<<dim3(1, 16), blk, 0, stream>>>(xw, wdec1, hdec, nullptr, 64, 1024);
  gemm_k<EPI_FLAT><<<dim3(1, 16), blk, 0, stream>>>(xa, a1, ha, nullptr, 64, 1024);
  gemm_k<EPI_BIAS_HEAD><<<gT, blk, 0, stream>>>(hdec, wdec2, csfb, tdecay, 1024, 64);
  gemm_k<EPI_SIGBIAS_HEAD><<<gT, blk, 0, stream>>>(ha, a2, iclr, a0, 1024, 64);

  k4_kfix<<<(BB * HH * TT) / 4, blk, 0, stream>>>(kbuf, kkb, kkib, iclr, k_k, k_a);
  k5_cumsum<<<BB * HH, 1024, 0, stream>>>(csfb, csbsb);
  k6_pass1<<<dim3(16, BB * HH), blk, 0, stream>>>(kkb, kkib, vT, vfT, vbT);
  k7_pass2<<<dim3(16, BB * HH), blk, 0, stream>>>(rbuf, kbuf, csfb, csbsb, vfT, vbT, ybuf);
  k8_gnorm<<<NBT, blk, 0, stream>>>(ybuf, gbuf, lnw, lnb, gnb);
  gemm_bf<EPI_OUT><<<gT, blk, 0, stream>>>(gnb, WtO, out);
}

// Round 3
// 433.513 us; speedup vs baseline: 5.0053x; 1.9219x over previous
//
#include <hip/hip_runtime.h>
#include <math.h>

#define BB 2
#define TT 1024
#define DD 1024
#define HH 16
#define KK 64
#define NBT 2048              // B*T
#define NE  2097152ULL        // B*T*D

typedef unsigned short u16;
typedef __attribute__((ext_vector_type(8))) short short8;   // 8 bf16 (4 VGPR)
typedef __attribute__((ext_vector_type(4))) short short4v;  // 4 bf16 (8B)
typedef __attribute__((ext_vector_type(4))) float f32x4;

__device__ __forceinline__ float bf2f(u16 u) {
  union { unsigned int i; float f; } v; v.i = ((unsigned int)u) << 16; return v.f;
}
__device__ __forceinline__ u16 f2bf(float x) {
  union { float f; unsigned int u; } v; v.f = x;
  unsigned int r = v.u + 0x7fffu + ((v.u >> 16) & 1u);
  return (u16)(r >> 16);
}
__device__ __forceinline__ f32x4 MFMA(short8 a, short8 b, f32x4 c) {
  return __builtin_amdgcn_mfma_f32_16x16x32_bf16(a, b, c, 0, 0, 0);
}
// XOR swizzle for [64 rows][128B] LDS tiles (G4: 128B rows are 32-way conflict)
__device__ __forceinline__ int swzb(int row, int kbyte) {
  return row * 128 + (kbyte ^ ((row & 7) << 4));
}
__device__ __forceinline__ void gload16(const void* g, void* l) {
  __builtin_amdgcn_global_load_lds((const __attribute__((address_space(1))) void*)g,
                                   (__attribute__((address_space(3))) void*)l, 16, 0, 0);
}

constexpr int EPI_FLAT = 0, EPI_BIAS_HEAD = 4, EPI_SIGBIAS_HEAD = 5;
constexpr int EPI_OUT = 0, EPI_GSILU = 1, EPI_HEADB = 2, EPI_VTB = 3;

// ---------------- K1: token shift + xxx + hmix = tanh(xxx @ W1) ----------------
__global__ __launch_bounds__(256)
void k1_shift_hmix(const float* __restrict__ x, const float* __restrict__ maa_x,
                   const float* __restrict__ W1, float* __restrict__ dxprev,
                   float* __restrict__ hmix) {
  __shared__ float xs[8 * 1024];
  int row0 = blockIdx.x * 8;
  int tid = threadIdx.x;
  for (int i = tid; i < 8 * 1024; i += 256) {
    int r = i >> 10, d = i & 1023;
    int row = row0 + r;
    int t = row & (TT - 1);
    size_t g = (size_t)row * DD + d;
    float xc = x[g];
    float xl = (t == 0) ? 0.f : x[g - DD];
    float xr = (t == TT - 1) ? 0.f : x[g + DD];
    float dx = 0.5f * (xl + xr) - xc;
    dxprev[g] = dx;
    xs[i] = xc + dx * maa_x[d];
  }
  __syncthreads();
  if (tid < 192) {
    float acc[8] = {0, 0, 0, 0, 0, 0, 0, 0};
    for (int d = 0; d < 1024; ++d) {
      float w = W1[(size_t)d * 192 + tid];
#pragma unroll
      for (int r = 0; r < 8; ++r) acc[r] += xs[r * 1024 + d] * w;
    }
#pragma unroll
    for (int r = 0; r < 8; ++r)
      hmix[(size_t)(row0 + r) * 192 + tid] = tanhf(acc[r]);
  }
}

// ---------------- K2: six mixed inputs; w,a fp32; k,v,r,g bf16 ----------------
__global__ __launch_bounds__(256)
void k2_mix6(const float* __restrict__ x, const float* __restrict__ dxprev,
             const float* __restrict__ hmix, const float* __restrict__ W2,
             const float* __restrict__ maa_w, const float* __restrict__ maa_k,
             const float* __restrict__ maa_v, const float* __restrict__ maa_r,
             const float* __restrict__ maa_g, const float* __restrict__ maa_a,
             float* __restrict__ xw, float* __restrict__ xa,
             u16* __restrict__ xk_b, u16* __restrict__ xv_b,
             u16* __restrict__ xr_b, u16* __restrict__ xg_b) {
  __shared__ float hs[8][192];
  int row0 = blockIdx.y * 8;
  int d = blockIdx.x * 256 + threadIdx.x;
  for (int i = threadIdx.x; i < 8 * 192; i += 256)
    hs[i / 192][i % 192] = hmix[(size_t)row0 * 192 + i];
  __syncthreads();
  float xv_[8], dx_[8];
#pragma unroll
  for (int r = 0; r < 8; ++r) {
    xv_[r] = x[(size_t)(row0 + r) * DD + d];
    dx_[r] = dxprev[(size_t)(row0 + r) * DD + d];
  }
  const float* maas[6] = {maa_w, maa_k, maa_v, maa_r, maa_g, maa_a};
#pragma unroll
  for (int s = 0; s < 6; ++s) {
    float acc[8] = {0, 0, 0, 0, 0, 0, 0, 0};
    for (int m = 0; m < 32; ++m) {
      float w = W2[(size_t)(s * 32 + m) * DD + d];
#pragma unroll
      for (int r = 0; r < 8; ++r) acc[r] += hs[r][s * 32 + m] * w;
    }
    float ma = maas[s][d];
#pragma unroll
    for (int r = 0; r < 8; ++r) {
      size_t idx = (size_t)(row0 + r) * DD + d;
      float val = xv_[r] + dx_[r] * (ma + acc[r]);
      if (s == 0) xw[idx] = val;
      else if (s == 5) xa[idx] = val;
      else if (s == 1) xk_b[idx] = f2bf(val);
      else if (s == 2) xv_b[idx] = f2bf(val);
      else if (s == 3) xr_b[idx] = f2bf(val);
      else xg_b[idx] = f2bf(val);
    }
  }
}

// ---------------- weight transpose fp32[k][n] -> bf16 [n][k] ----------------
__global__ __launch_bounds__(256)
void wtrans(const float* __restrict__ W, u16* __restrict__ Wt) {
  __shared__ float tl[64][65];
  int k0 = blockIdx.x * 64, n0 = blockIdx.y * 64;
  int tid = threadIdx.x;
  int r = tid >> 2, c0 = (tid & 3) * 16;
#pragma unroll
  for (int j = 0; j < 16; j += 4) {
    f32x4 v = *(const f32x4*)(W + (size_t)(k0 + r) * 1024 + n0 + c0 + j);
    tl[r][c0 + j + 0] = v[0]; tl[r][c0 + j + 1] = v[1];
    tl[r][c0 + j + 2] = v[2]; tl[r][c0 + j + 3] = v[3];
  }
  __syncthreads();
  u16 o[16];
#pragma unroll
  for (int j = 0; j < 16; ++j) o[j] = f2bf(tl[c0 + j][r]);
  *(short8*)(Wt + (size_t)(n0 + r) * 1024 + k0 + c0) = *(short8*)(o);
  *(short8*)(Wt + (size_t)(n0 + r) * 1024 + k0 + c0 + 8) = *(short8*)(o + 8);
}

// ---------------- bf16 MFMA GEMM: C(2048 x 1024) = A(2048 x 1024) @ Bt^T ----------------
template <int EPI>
__global__ __launch_bounds__(256)
void gemm_bf(const u16* __restrict__ A, const u16* __restrict__ Bt,
             void* __restrict__ Cv) {
  __shared__ u16 As[128 * 32];
  __shared__ u16 Bs[64 * 32];
  int m0 = blockIdx.y * 128, n0 = blockIdx.x * 64;
  int tid = threadIdx.x, w = tid >> 6, lane = tid & 63;
  int mq = w >> 1, nq = w & 1;
  f32x4 acc[4][2];
#pragma unroll
  for (int i = 0; i < 4; ++i)
#pragma unroll
    for (int j = 0; j < 2; ++j) acc[i][j] = {0.f, 0.f, 0.f, 0.f};
  for (int k0 = 0; k0 < 1024; k0 += 32) {
#pragma unroll
    for (int c2 = 0; c2 < 2; ++c2) {
      int ch = w * 2 + c2;
      int row = ch * 16 + (lane >> 2);
      gload16(A + (size_t)(m0 + row) * 1024 + k0 + (lane & 3) * 8, As + ch * 512);
    }
    {
      int row = w * 16 + (lane >> 2);
      gload16(Bt + (size_t)(n0 + row) * 1024 + k0 + (lane & 3) * 8, Bs + w * 512);
    }
    __syncthreads();
    short8 a[4], b[2];
#pragma unroll
    for (int mf = 0; mf < 4; ++mf)
      a[mf] = *(const short8*)(As + (mq * 64 + mf * 16 + (lane & 15)) * 32 + (lane >> 4) * 8);
#pragma unroll
    for (int nf = 0; nf < 2; ++nf)
      b[nf] = *(const short8*)(Bs + (nq * 32 + nf * 16 + (lane & 15)) * 32 + (lane >> 4) * 8);
#pragma unroll
    for (int mf = 0; mf < 4; ++mf)
#pragma unroll
      for (int nf = 0; nf < 2; ++nf) acc[mf][nf] = MFMA(a[mf], b[nf], acc[mf][nf]);
    __syncthreads();
  }
#pragma unroll
  for (int mf = 0; mf < 4; ++mf) {
#pragma unroll
    for (int nf = 0; nf < 2; ++nf) {
      int mb = m0 + mq * 64 + mf * 16 + (lane >> 4) * 4;
      int n = n0 + nq * 32 + nf * 16 + (lane & 15);
      if constexpr (EPI == EPI_VTB) {
        u16 o[4];
#pragma unroll
        for (int r = 0; r < 4; ++r) o[r] = f2bf(acc[mf][nf][r]);
        int b2 = mb >> 10, t = mb & 1023;
        u16* C = (u16*)Cv;
        *(short4v*)(C + (((size_t)(b2 * HH + (n >> 6))) * KK + (n & 63)) * TT + t) = *(short4v*)o;
      } else {
#pragma unroll
        for (int r = 0; r < 4; ++r) {
          int m = mb + r;
          float v = acc[mf][nf][r];
          if constexpr (EPI == EPI_OUT) {
            ((float*)Cv)[(size_t)m * 1024 + n] = v;
          } else if constexpr (EPI == EPI_GSILU) {
            ((float*)Cv)[(size_t)m * 1024 + n] = v / (1.f + __expf(-v));
          } else {  // EPI_HEADB
            int b2 = m >> 10, t = m & 1023;
            ((u16*)Cv)[(((size_t)(b2 * HH + (n >> 6))) * TT + t) * KK + (n & 63)] = f2bf(v);
          }
        }
      }
    }
  }
}

// ---------------- skinny split-K fp32 GEMM: P[kb] = A(2048x1024)[:,kb*128:+128] @ B ----------------
__global__ __launch_bounds__(256)
void skinny_gemm(const float* __restrict__ A, const float* __restrict__ B,
                 float* __restrict__ P) {
  __shared__ float As[32][129];
  __shared__ float Bs[128][64];
  int m0 = blockIdx.x * 32;
  int kb = blockIdx.y;  // 0..7
  int tid = threadIdx.x;
  for (int i = tid; i < 1024; i += 256) {
    int r = i >> 5, c4 = (i & 31) * 4;
    f32x4 v = *(const f32x4*)(A + (size_t)(m0 + r) * 1024 + kb * 128 + c4);
    As[r][c4 + 0] = v[0]; As[r][c4 + 1] = v[1];
    As[r][c4 + 2] = v[2]; As[r][c4 + 3] = v[3];
  }
  for (int i = tid; i < 2048; i += 256) {
    int r = i >> 4, c4 = (i & 15) * 4;
    f32x4 v = *(const f32x4*)(B + (size_t)(kb * 128 + r) * 64 + c4);
    Bs[r][c4 + 0] = v[0]; Bs[r][c4 + 1] = v[1];
    Bs[r][c4 + 2] = v[2]; Bs[r][c4 + 3] = v[3];
  }
  __syncthreads();
  int col = tid & 63, rg = tid >> 6;  // 4 waves: 8 rows each
  float acc[8] = {};
  for (int k = 0; k < 128; ++k) {
    float b = Bs[k][col];
#pragma unroll
    for (int r = 0; r < 8; ++r) acc[r] += As[rg * 8 + r][k] * b;
  }
#pragma unroll
  for (int r = 0; r < 8; ++r)
    P[((size_t)kb * NBT + m0 + rg * 8 + r) * 64 + col] = acc[r];
}

// ---------------- skinny reduce: C = epi(sum_kb P[kb]) ----------------
template <int TANH>
__global__ __launch_bounds__(256)
void skinny_reduce(const float* __restrict__ P, float* __restrict__ C) {
  size_t i = (size_t)blockIdx.x * 256 + threadIdx.x;  // 131072 total
  float s = 0.f;
#pragma unroll
  for (int kb = 0; kb < 8; ++kb) s += P[(size_t)kb * 131072 + i];
  C[i] = TANH ? tanhf(s) : s;
}

// ---------------- fp32 GEMM (K=64 LoRA-up paths) ----------------
template <int EPI>
__global__ __launch_bounds__(256)
void gemm_k(const float* __restrict__ A, const float* __restrict__ Bm,
            float* __restrict__ C, const float* __restrict__ bias, int N, int Kd) {
  __shared__ float As[16][132];
  __shared__ float Bs[16][68];
  int n0 = blockIdx.x * 64;
  int m0 = blockIdx.y * 128;
  int tid = threadIdx.x;
  int tx = tid & 15;
  int ty = tid >> 4;
  float acc[8][4] = {};
  for (int k0 = 0; k0 < Kd; k0 += 16) {
#pragma unroll
    for (int i = tid; i < 2048; i += 256) {
      int mm = i >> 4, kk2 = i & 15;
      As[kk2][mm] = A[(size_t)(m0 + mm) * Kd + (k0 + kk2)];
    }
#pragma unroll
    for (int i = tid; i < 1024; i += 256) {
      int kk2 = i >> 6, nn = i & 63;
      Bs[kk2][nn] = Bm[(size_t)(k0 + kk2) * N + (n0 + nn)];
    }
    __syncthreads();
#pragma unroll
    for (int kk2 = 0; kk2 < 16; ++kk2) {
      float a[8], b[4];
#pragma unroll
      for (int r = 0; r < 8; ++r) a[r] = As[kk2][ty * 8 + r];
#pragma unroll
      for (int c = 0; c < 4; ++c) b[c] = Bs[kk2][tx * 4 + c];
#pragma unroll
      for (int r = 0; r < 8; ++r)
#pragma unroll
        for (int c = 0; c < 4; ++c) acc[r][c] += a[r] * b[c];
    }
    __syncthreads();
  }
#pragma unroll
  for (int r = 0; r < 8; ++r) {
    int m = m0 + ty * 8 + r;
    int bb2 = m >> 10, t = m & 1023;
#pragma unroll
    for (int c = 0; c < 4; ++c) {
      int n = n0 + tx * 4 + c;
      float vv = acc[r][c];
      if constexpr (EPI == EPI_BIAS_HEAD) vv += bias[n];
      if constexpr (EPI == EPI_SIGBIAS_HEAD) vv = 1.f / (1.f + expf(-(vv + bias[n])));
      if constexpr (EPI == EPI_FLAT)
        C[(size_t)m * N + n] = vv;
      else
        C[(((size_t)(bb2 * HH + (n >> 6))) * TT + t) * KK + (n & 63)] = vv;
    }
  }
}

// ---------------- K4: kk normalize, kki, k scale (bf16 in/out) ----------------
__global__ __launch_bounds__(256)
void k4_kfix(u16* __restrict__ kbuf, u16* __restrict__ kkbuf, u16* __restrict__ kkibuf,
             const float* __restrict__ iclr, const float* __restrict__ k_k,
             const float* __restrict__ k_a) {
  int gid = blockIdx.x * 4 + (threadIdx.x >> 6);
  int lane = threadIdx.x & 63;
  size_t base = (size_t)gid * 64 + lane;
  int h = (gid >> 10) & (HH - 1);
  int d = h * 64 + lane;
  float kv = bf2f(kbuf[base]);
  float ic = iclr[base];
  float kkh = kv * k_k[d];
  float ss = kkh * kkh;
#pragma unroll
  for (int off = 32; off > 0; off >>= 1) ss += __shfl_xor(ss, off);
  float nrm = fmaxf(sqrtf(ss), 1e-12f);
  float kkv = kkh / nrm;
  kkbuf[base] = f2bf(kkv);
  kkibuf[base] = f2bf(kkv * ic);
  kbuf[base] = f2bf(kv * (1.f + (ic - 1.f) * k_a[d]));
}

// ---------------- K5: cumsum + clipped csf/csbs (fp32) ----------------
__global__ __launch_bounds__(1024)
void k5_cumsum(float* __restrict__ csf, float* __restrict__ csbs) {
  __shared__ float part[16][64];
  __shared__ float cs512s[64], wh512s[64];
  int bh = blockIdx.x;
  int lane = threadIdx.x & 63;
  int c = threadIdx.x >> 6;
  size_t base = (size_t)bh * TT * KK + (size_t)c * 64 * KK + lane;
  float p = 0.f;
  for (int i = 0; i < 64; ++i) {
    float wr = csf[base + (size_t)i * KK];
    float wh = -expf(wr);
    csbs[base + (size_t)i * KK] = wh;
    p += wh;
  }
  part[c][lane] = p;
  __syncthreads();
  if (threadIdx.x < 64) {
    float run = 0.f;
#pragma unroll
    for (int cc = 0; cc < 16; ++cc) {
      float tv = part[cc][lane];
      part[cc][lane] = run;
      run += tv;
    }
  }
  __syncthreads();
  float cs = part[c][lane];
  for (int i = 0; i < 64; ++i) {
    float wh = csbs[base + (size_t)i * KK];
    cs += wh;
    csbs[base + (size_t)i * KK] = cs;
    if (c == 8 && i == 0) { cs512s[lane] = cs; wh512s[lane] = wh; }
  }
  __syncthreads();
  float cs512 = cs512s[lane];
  float csb512 = cs512 - wh512s[lane];
  for (int i = 0; i < 64; ++i) {
    size_t g = base + (size_t)i * KK;
    float wr = csf[g];
    float wh = -expf(wr);
    float cc2 = csbs[g];
    csf[g] = fminf(fmaxf(cc2 - cs512, -60.f), 60.f);
    csbs[g] = fminf(fmaxf((cc2 - wh) - csb512, -60.f), 60.f);
  }
}

// ---------------- attention tile helpers (bf16 MFMA) ----------------
__device__ __forceinline__ void stage_copy(const u16* src, int rstride, u16* lds) {
  int tid = threadIdx.x;
#pragma unroll
  for (int c = 0; c < 2; ++c) {
    int ch = tid + c * 256;
    int row = ch >> 3, slot = ch & 7;
    short8 v = *(const short8*)(src + (size_t)row * rstride + slot * 8);
    *(short8*)((char*)lds + swzb(row, slot * 16)) = v;
  }
}
template <int PLUS>
__device__ __forceinline__ void stage_kexp(const u16* ksrc, const float* csrc, u16* lds) {
  int tid = threadIdx.x;
#pragma unroll
  for (int c = 0; c < 2; ++c) {
    int ch = tid + c * 256;
    int row = ch >> 3, slot = ch & 7;
    short8 kv = *(const short8*)(ksrc + (size_t)row * 64 + slot * 8);
    const float* cp = csrc + (size_t)row * 64 + slot * 8;
    u16 o[8];
#pragma unroll
    for (int j = 0; j < 8; ++j) {
      float cs = cp[j];
      o[j] = f2bf(bf2f((u16)kv[j]) * __expf(PLUS ? cs : -cs));
    }
    *(short8*)((char*)lds + swzb(row, slot * 16)) = *(short8*)o;
  }
}
template <int MASK>  // 0 none, 1 jl<il, 2 jl>il, 3 jl<=il
__device__ __forceinline__ void store_S(const f32x4 s[4], u16* St, int lane, int w) {
  int ig0 = w * 16 + (lane >> 4) * 4;
#pragma unroll
  for (int jf = 0; jf < 4; ++jf) {
    int jl = jf * 16 + (lane & 15);
#pragma unroll
    for (int r = 0; r < 4; ++r) {
      int il = ig0 + r;
      float v = s[jf][r];
      if (MASK == 1 && !(jl < il)) v = 0.f;
      if (MASK == 2 && !(jl > il)) v = 0.f;
      if (MASK == 3 && !(jl <= il)) v = 0.f;
      *(u16*)((char*)St + swzb(il, jl * 2)) = f2bf(v);
    }
  }
}
__device__ __forceinline__ void smm(const short8 afr[2], const u16* Kt, f32x4 s[4], int lane) {
#pragma unroll
  for (int jf = 0; jf < 4; ++jf) {
    f32x4 z = {0.f, 0.f, 0.f, 0.f};
#pragma unroll
    for (int ks = 0; ks < 2; ++ks) {
      short8 kb = *(const short8*)((const char*)Kt + swzb(jf * 16 + (lane & 15), ks * 64 + (lane >> 4) * 16));
      z = MFMA(afr[ks], kb, z);
    }
    s[jf] = z;
  }
}
__device__ __forceinline__ void pv(const u16* St, const u16* Vt, f32x4 acc[4], int lane, int w) {
#pragma unroll
  for (int ks = 0; ks < 2; ++ks) {
    short8 a = *(const short8*)((const char*)St + swzb(w * 16 + (lane & 15), ks * 64 + (lane >> 4) * 16));
#pragma unroll
    for (int cf = 0; cf < 4; ++cf) {
      short8 b = *(const short8*)((const char*)Vt + swzb(cf * 16 + (lane & 15), ks * 64 + (lane >> 4) * 16));
      acc[cf] = MFMA(a, b, acc[cf]);
    }
  }
}

// ---------------- K6: pass 1 ----------------
__global__ __launch_bounds__(256)
void k6_pass1(const u16* __restrict__ kk, const u16* __restrict__ kki,
              const u16* __restrict__ vT, u16* __restrict__ vfT, u16* __restrict__ vbT) {
  __shared__ u16 Kt[4096], Vt[4096], St[4096];
  int bh = blockIdx.y, it = blockIdx.x, i0 = it * 64;
  size_t hb = (size_t)bh * 65536;
  int tid = threadIdx.x, w = tid >> 6, lane = tid & 63;
  int iw = i0 + w * 16;
  short8 afr[2];
  {
    int row = iw + (lane & 15);
#pragma unroll
    for (int s = 0; s < 2; ++s)
      afr[s] = *(const short8*)(kki + hb + (size_t)row * 64 + s * 32 + (lane >> 4) * 8);
  }
  f32x4 af[4], ab[4];
#pragma unroll
  for (int c = 0; c < 4; ++c) { af[c] = {0.f, 0.f, 0.f, 0.f}; ab[c] = {0.f, 0.f, 0.f, 0.f}; }
  for (int jt = 0; jt < 16; ++jt) {
    int j0 = jt * 64;
    __syncthreads();
    stage_copy(kk + hb + (size_t)j0 * 64, 64, Kt);
    stage_copy(vT + hb + j0, 1024, Vt);
    __syncthreads();
    f32x4 s[4];
    smm(afr, Kt, s, lane);
    if (jt == it) {
      store_S<1>(s, St, lane, w);
      __syncthreads();
      pv(St, Vt, af, lane, w);
      __syncthreads();
      store_S<2>(s, St, lane, w);
      __syncthreads();
      pv(St, Vt, ab, lane, w);
    } else {
      store_S<0>(s, St, lane, w);
      __syncthreads();
      if (jt < it) pv(St, Vt, af, lane, w);
      else pv(St, Vt, ab, lane, w);
    }
  }
#pragma unroll
  for (int cf = 0; cf < 4; ++cf) {
    int c = cf * 16 + (lane & 15);
    int i = iw + (lane >> 4) * 4;
    size_t g = hb + (size_t)c * 1024 + i;
    short4v vv = *(const short4v*)(vT + g);
    u16 o1[4], o2[4];
#pragma unroll
    for (int r = 0; r < 4; ++r) {
      float v0 = bf2f((u16)vv[r]);
      o1[r] = f2bf(v0 - af[cf][r]);
      o2[r] = f2bf(v0 - ab[cf][r]);
    }
    *(short4v*)(vfT + g) = *(short4v*)o1;
    *(short4v*)(vbT + g) = *(short4v*)o2;
  }
}

// ---------------- K7: pass 2 ----------------
__global__ __launch_bounds__(256)
void k7_pass2(const u16* __restrict__ rb, const u16* __restrict__ kb,
              const float* __restrict__ csf, const float* __restrict__ csbs,
              const u16* __restrict__ vfT, const u16* __restrict__ vbT,
              float* __restrict__ y) {
  __shared__ u16 Kt[4096], Vt[4096], St[4096];
  int bh = blockIdx.y, it = blockIdx.x, i0 = it * 64;
  size_t hb = (size_t)bh * 65536;
  int tid = threadIdx.x, w = tid >> 6, lane = tid & 63;
  int iw = i0 + w * 16;
  short8 rf[2], rbk[2];
  {
    int row = iw + (lane & 15);
#pragma unroll
    for (int s = 0; s < 2; ++s) {
      int k = s * 32 + (lane >> 4) * 8;
      const u16* rp = rb + hb + (size_t)row * 64 + k;
      const float* cf = csf + hb + (size_t)row * 64 + k;
      const float* cb = csbs + hb + (size_t)row * 64 + k;
      u16 a[8], b[8];
#pragma unroll
      for (int j = 0; j < 8; ++j) {
        float rv = bf2f(rp[j]);
        a[j] = f2bf(rv * __expf(cf[j]));
        b[j] = f2bf(rv * __expf(-cb[j]));
      }
      rf[s] = *(short8*)a;
      rbk[s] = *(short8*)b;
    }
  }
  f32x4 acc[4];
#pragma unroll
  for (int c = 0; c < 4; ++c) acc[c] = {0.f, 0.f, 0.f, 0.f};
  for (int jt = 0; jt < 16; ++jt) {
    int j0 = jt * 64;
    if (jt <= it) {
      __syncthreads();
      stage_kexp<0>(kb + hb + (size_t)j0 * 64, csf + hb + (size_t)j0 * 64, Kt);
      stage_copy(vfT + hb + j0, 1024, Vt);
      __syncthreads();
      f32x4 s[4];
      smm(rf, Kt, s, lane);
      if (jt == it) store_S<3>(s, St, lane, w);
      else store_S<0>(s, St, lane, w);
      __syncthreads();
      pv(St, Vt, acc, lane, w);
    }
    if (jt >= it) {
      __syncthreads();
      stage_kexp<1>(kb + hb + (size_t)j0 * 64, csbs + hb + (size_t)j0 * 64, Kt);
      stage_copy(vbT + hb + j0, 1024, Vt);
      __syncthreads();
      f32x4 s[4];
      smm(rbk, Kt, s, lane);
      if (jt == it) store_S<2>(s, St, lane, w);
      else store_S<0>(s, St, lane, w);
      __syncthreads();
      pv(St, Vt, acc, lane, w);
    }
  }
#pragma unroll
  for (int cf = 0; cf < 4; ++cf) {
    int c = cf * 16 + (lane & 15);
#pragma unroll
    for (int r = 0; r < 4; ++r) {
      int i = iw + (lane >> 4) * 4 + r;
      y[hb + (size_t)i * 64 + c] = acc[cf][r];
    }
  }
}

// ---------------- K8: GroupNorm * ln + bias, * g -> bf16 ----------------
__global__ __launch_bounds__(256)
void k8_gnorm(const float* __restrict__ y, const float* __restrict__ g,
              const float* __restrict__ lnw, const float* __restrict__ lnb,
              u16* __restrict__ outb) {
  int bt = blockIdx.x;
  int b = bt >> 10, t = bt & 1023;
  int wv = threadIdx.x >> 6, lane = threadIdx.x & 63;
  for (int h = wv; h < HH; h += 4) {
    size_t idx = (((size_t)(b * HH + h)) * TT + t) * KK + lane;
    float v = y[idx];
    float s1 = v, s2 = v * v;
#pragma unroll
    for (int off = 32; off > 0; off >>= 1) {
      s1 += __shfl_xor(s1, off);
      s2 += __shfl_xor(s2, off);
    }
    float mu = s1 * (1.f / 64.f);
    float var = s2 * (1.f / 64.f) - mu * mu;
    float xn = (v - mu) * rsqrtf(var + 6.4e-4f);
    int d = h * 64 + lane;
    float o = xn * lnw[d] + lnb[d];
    outb[(size_t)bt * DD + d] = f2bf(o * g[(size_t)bt * DD + d]);
  }
}

extern "C" void kernel_launch(void* const* d_in, const int* in_sizes, int n_in,
                              void* d_out, int out_size, void* d_ws, size_t ws_size,
                              hipStream_t stream) {
  const float* x      = (const float*)d_in[0];
  const float* maa_x  = (const float*)d_in[1];
  const float* maa_w  = (const float*)d_in[2];
  const float* maa_k  = (const float*)d_in[3];
  const float* maa_v  = (const float*)d_in[4];
  const float* maa_r  = (const float*)d_in[5];
  const float* maa_g  = (const float*)d_in[6];
  const float* maa_a  = (const float*)d_in[7];
  const float* w1mix  = (const float*)d_in[8];
  const float* w2mix  = (const float*)d_in[9];
  const float* tdecay = (const float*)d_in[10];
  const float* wdec1  = (const float*)d_in[11];
  const float* wdec2  = (const float*)d_in[12];
  const float* a0     = (const float*)d_in[13];
  const float* a1     = (const float*)d_in[14];
  const float* a2     = (const float*)d_in[15];
  const float* k_k    = (const float*)d_in[16];
  const float* k_a    = (const float*)d_in[17];
  const float* W_r    = (const float*)d_in[18];
  const float* W_k    = (const float*)d_in[19];
  const float* W_v    = (const float*)d_in[20];
  const float* W_g    = (const float*)d_in[21];
  const float* W_o    = (const float*)d_in[22];
  const float* lnw    = (const float*)d_in[23];
  const float* lnb    = (const float*)d_in[24];
  float* out = (float*)d_out;

  const size_t NEf = NE;
  float* F = (float*)d_ws;
  float* dxprev = F;               // NE (reused as ybuf)
  float* ybuf   = F;
  float* xw     = F + 1 * NEf;
  float* xa     = F + 2 * NEf;
  float* csfb   = F + 3 * NEf;
  float* csbsb  = F + 4 * NEf;
  float* iclr   = F + 5 * NEf;
  float* gbuf   = F + 6 * NEf;
  float* hmix   = F + 7 * NEf;                 // 393216
  float* hdec   = F + 7 * NEf + 524288;        // 131072
  float* ha     = F + 7 * NEf + 786432;        // 131072
  float* Ppart  = F + 7 * NEf + 917504;        // 1048576 (8x2048x64)
  u16* U = (u16*)(F + 8 * NEf);
  u16* xr_b = U + 0 * NEf;
  u16* xk_b = U + 1 * NEf;
  u16* xv_b = U + 2 * NEf;
  u16* xg_b = U + 3 * NEf;
  u16* rbuf = U + 4 * NEf;
  u16* kbuf = U + 5 * NEf;
  u16* vT   = U + 6 * NEf;
  u16* kkb  = U + 7 * NEf;
  u16* kkib = U + 8 * NEf;
  u16* vfT  = U + 9 * NEf;
  u16* vbT  = U + 10 * NEf;
  u16* gnb  = U + 11 * NEf;
  u16* WtR  = U + 12 * NEf;
  u16* WtK  = U + 12 * NEf + 1048576;
  u16* WtV  = U + 12 * NEf + 2097152;
  u16* WtG  = U + 12 * NEf + 3145728;
  u16* WtO  = U + 12 * NEf + 4194304;

  dim3 blk(256);
  dim3 gT(16, 16);
  wtrans<<<gT, blk, 0, stream>>>(W_r, WtR);
  wtrans<<<gT, blk, 0, stream>>>(W_k, WtK);
  wtrans<<<gT, blk, 0, stream>>>(W_v, WtV);
  wtrans<<<gT, blk, 0, stream>>>(W_g, WtG);
  wtrans<<<gT, blk, 0, stream>>>(W_o, WtO);

  k1_shift_hmix<<<NBT / 8, blk, 0, stream>>>(x, maa_x, w1mix, dxprev, hmix);
  k2_mix6<<<dim3(4, NBT / 8), blk, 0, stream>>>(x, dxprev, hmix, w2mix, maa_w, maa_k,
                                                maa_v, maa_r, maa_g, maa_a,
                                                xw, xa, xk_b, xv_b, xr_b, xg_b);

  gemm_bf<EPI_HEADB><<<gT, blk, 0, stream>>>(xr_b, WtR, rbuf);
  gemm_bf<EPI_HEADB><<<gT, blk, 0, stream>>>(xk_b, WtK, kbuf);
  gemm_bf<EPI_VTB><<<gT, blk, 0, stream>>>(xv_b, WtV, vT);
  gemm_bf<EPI_GSILU><<<gT, blk, 0, stream>>>(xg_b, WtG, gbuf);

  // skinny LoRA-down paths (split-K, fp32)
  skinny_gemm<<<dim3(64, 8), blk, 0, stream>>>(xw, wdec1, Ppart);
  skinny_reduce<1><<<512, blk, 0, stream>>>(Ppart, hdec);
  skinny_gemm<<<dim3(64, 8), blk, 0, stream>>>(xa, a1, Ppart);
  skinny_reduce<0><<<512, blk, 0, stream>>>(Ppart, ha);

  gemm_k<EPI_BIAS_HEAD><<<gT, blk, 0, stream>>>(hdec, wdec2, csfb, tdecay, 1024, 64);
  gemm_k<EPI_SIGBIAS_HEAD><<<gT, blk, 0, stream>>>(ha, a2, iclr, a0, 1024, 64);

  k4_kfix<<<(BB * HH * TT) / 4, blk, 0, stream>>>(kbuf, kkb, kkib, iclr, k_k, k_a);
  k5_cumsum<<<BB * HH, 1024, 0, stream>>>(csfb, csbsb);
  k6_pass1<<<dim3(16, BB * HH), blk, 0, stream>>>(kkb, kkib, vT, vfT, vbT);
  k7_pass2<<<dim3(16, BB * HH), blk, 0, stream>>>(rbuf, kbuf, csfb, csbsb, vfT, vbT, ybuf);
  k8_gnorm<<<NBT, blk, 0, stream>>>(ybuf, gbuf, lnw, lnb, gnb);
  gemm_bf<EPI_OUT><<<gT, blk, 0, stream>>>(gnb, WtO, out);
}

// Round 4
// 318.303 us; speedup vs baseline: 6.8169x; 1.3620x over previous
//
#include <hip/hip_runtime.h>
#include <math.h>

#define BB 2
#define TT 1024
#define DD 1024
#define HH 16
#define KK 64
#define NBT 2048              // B*T
#define NE  2097152ULL        // B*T*D

typedef unsigned short u16;
typedef __attribute__((ext_vector_type(8))) short short8;   // 8 bf16 (4 VGPR)
typedef __attribute__((ext_vector_type(4))) short short4v;  // 4 bf16 (8B)
typedef __attribute__((ext_vector_type(4))) float f32x4;

__device__ __forceinline__ float bf2f(u16 u) {
  union { unsigned int i; float f; } v; v.i = ((unsigned int)u) << 16; return v.f;
}
__device__ __forceinline__ u16 f2bf(float x) {
  union { float f; unsigned int u; } v; v.f = x;
  unsigned int r = v.u + 0x7fffu + ((v.u >> 16) & 1u);
  return (u16)(r >> 16);
}
__device__ __forceinline__ f32x4 MFMA(short8 a, short8 b, f32x4 c) {
  return __builtin_amdgcn_mfma_f32_16x16x32_bf16(a, b, c, 0, 0, 0);
}
// XOR swizzle for [64 rows][128B] LDS tiles (G4: 128B rows are 32-way conflict)
__device__ __forceinline__ int swzb(int row, int kbyte) {
  return row * 128 + (kbyte ^ ((row & 7) << 4));
}
__device__ __forceinline__ void gload16(const void* g, void* l) {
  __builtin_amdgcn_global_load_lds((const __attribute__((address_space(1))) void*)g,
                                   (__attribute__((address_space(3))) void*)l, 16, 0, 0);
}

constexpr int EPI_FLAT = 0, EPI_BIAS_HEAD = 4, EPI_SIGBIAS_HEAD = 5;
constexpr int EPI_OUT = 0;

// ---------------- K1a: xxx = x + dx * maa_x (elementwise) ----------------
__global__ __launch_bounds__(256)
void k1_xxx(const float* __restrict__ x, const float* __restrict__ maa_x,
            float* __restrict__ xxx) {
  int row = blockIdx.x;
  int t = row & (TT - 1);
  int d0 = threadIdx.x * 4;
  size_t g = (size_t)row * DD + d0;
  f32x4 xc = *(const f32x4*)(x + g);
  f32x4 xl = {0.f, 0.f, 0.f, 0.f}, xr = {0.f, 0.f, 0.f, 0.f};
  if (t != 0) xl = *(const f32x4*)(x + g - DD);
  if (t != TT - 1) xr = *(const f32x4*)(x + g + DD);
  f32x4 mx = *(const f32x4*)(maa_x + d0);
  f32x4 o;
#pragma unroll
  for (int j = 0; j < 4; ++j)
    o[j] = xc[j] + (0.5f * (xl[j] + xr[j]) - xc[j]) * mx[j];
  *(f32x4*)(xxx + g) = o;
}

// ---------------- skinny split-K fp32 GEMM: P[kb] = A[:,kb*128:+128] @ B[kb*128:+128, n0:n0+64]
__global__ __launch_bounds__(256)
void skinny_gemm(const float* __restrict__ A, const float* __restrict__ B,
                 float* __restrict__ P, int N) {
  __shared__ float As[32][129];
  __shared__ float Bs[128][64];
  int m0 = blockIdx.x * 32;
  int kb = blockIdx.y;      // 0..7
  int n0 = blockIdx.z * 64; // N tiles
  int tid = threadIdx.x;
  for (int i = tid; i < 1024; i += 256) {
    int r = i >> 5, c4 = (i & 31) * 4;
    f32x4 v = *(const f32x4*)(A + (size_t)(m0 + r) * 1024 + kb * 128 + c4);
    As[r][c4 + 0] = v[0]; As[r][c4 + 1] = v[1];
    As[r][c4 + 2] = v[2]; As[r][c4 + 3] = v[3];
  }
  for (int i = tid; i < 2048; i += 256) {
    int r = i >> 4, c4 = (i & 15) * 4;
    f32x4 v = *(const f32x4*)(B + (size_t)(kb * 128 + r) * N + n0 + c4);
    Bs[r][c4 + 0] = v[0]; Bs[r][c4 + 1] = v[1];
    Bs[r][c4 + 2] = v[2]; Bs[r][c4 + 3] = v[3];
  }
  __syncthreads();
  int col = tid & 63, rg = tid >> 6;  // 4 waves: 8 rows each
  float acc[8] = {};
  for (int k = 0; k < 128; ++k) {
    float b = Bs[k][col];
#pragma unroll
    for (int r = 0; r < 8; ++r) acc[r] += As[rg * 8 + r][k] * b;
  }
#pragma unroll
  for (int r = 0; r < 8; ++r)
    P[((size_t)kb * NBT + m0 + rg * 8 + r) * N + n0 + col] = acc[r];
}

// ---------------- reduce 8 partials: C = epi(sum_kb P[kb]) ----------------
template <int TANH>
__global__ __launch_bounds__(256)
void reduce8(const float* __restrict__ P, float* __restrict__ C, int total) {
  size_t i = (size_t)blockIdx.x * 256 + threadIdx.x;
  float s = 0.f;
#pragma unroll
  for (int kb = 0; kb < 8; ++kb) s += P[(size_t)kb * total + i];
  C[i] = TANH ? tanhf(s) : s;
}

// ---------------- K2: six mixed inputs (shift recomputed inline) ----------------
__global__ __launch_bounds__(256)
void k2_mix6(const float* __restrict__ x, const float* __restrict__ hmix,
             const float* __restrict__ W2,
             const float* __restrict__ maa_w, const float* __restrict__ maa_k,
             const float* __restrict__ maa_v, const float* __restrict__ maa_r,
             const float* __restrict__ maa_g, const float* __restrict__ maa_a,
             float* __restrict__ xw, float* __restrict__ xa,
             u16* __restrict__ xk_b, u16* __restrict__ xv_b,
             u16* __restrict__ xr_b, u16* __restrict__ xg_b) {
  __shared__ float hs[8][192];
  int row0 = blockIdx.y * 8;
  int d = blockIdx.x * 256 + threadIdx.x;
  for (int i = threadIdx.x; i < 8 * 192; i += 256)
    hs[i / 192][i % 192] = hmix[(size_t)row0 * 192 + i];
  __syncthreads();
  float xv_[8], dx_[8];
#pragma unroll
  for (int r = 0; r < 8; ++r) {
    int row = row0 + r;
    int t = row & (TT - 1);
    size_t g = (size_t)row * DD + d;
    float xc = x[g];
    float xl = (t == 0) ? 0.f : x[g - DD];
    float xr2 = (t == TT - 1) ? 0.f : x[g + DD];
    xv_[r] = xc;
    dx_[r] = 0.5f * (xl + xr2) - xc;
  }
  const float* maas[6] = {maa_w, maa_k, maa_v, maa_r, maa_g, maa_a};
#pragma unroll
  for (int s = 0; s < 6; ++s) {
    float acc[8] = {0, 0, 0, 0, 0, 0, 0, 0};
    for (int m = 0; m < 32; ++m) {
      float w = W2[(size_t)(s * 32 + m) * DD + d];
#pragma unroll
      for (int r = 0; r < 8; ++r) acc[r] += hs[r][s * 32 + m] * w;
    }
    float ma = maas[s][d];
#pragma unroll
    for (int r = 0; r < 8; ++r) {
      size_t idx = (size_t)(row0 + r) * DD + d;
      float val = xv_[r] + dx_[r] * (ma + acc[r]);
      if (s == 0) xw[idx] = val;
      else if (s == 5) xa[idx] = val;
      else if (s == 1) xk_b[idx] = f2bf(val);
      else if (s == 2) xv_b[idx] = f2bf(val);
      else if (s == 3) xr_b[idx] = f2bf(val);
      else xg_b[idx] = f2bf(val);
    }
  }
}

// ---------------- weight transpose fp32[k][n] -> bf16 [n][k] ----------------
__global__ __launch_bounds__(256)
void wtrans(const float* __restrict__ W, u16* __restrict__ Wt) {
  __shared__ float tl[64][65];
  int k0 = blockIdx.x * 64, n0 = blockIdx.y * 64;
  int tid = threadIdx.x;
  int r = tid >> 2, c0 = (tid & 3) * 16;
#pragma unroll
  for (int j = 0; j < 16; j += 4) {
    f32x4 v = *(const f32x4*)(W + (size_t)(k0 + r) * 1024 + n0 + c0 + j);
    tl[r][c0 + j + 0] = v[0]; tl[r][c0 + j + 1] = v[1];
    tl[r][c0 + j + 2] = v[2]; tl[r][c0 + j + 3] = v[3];
  }
  __syncthreads();
  u16 o[16];
#pragma unroll
  for (int j = 0; j < 16; ++j) o[j] = f2bf(tl[c0 + j][r]);
  *(short8*)(Wt + (size_t)(n0 + r) * 1024 + k0 + c0) = *(short8*)(o);
  *(short8*)(Wt + (size_t)(n0 + r) * 1024 + k0 + c0 + 8) = *(short8*)(o + 8);
}

// ---------------- fused 4-way bf16 MFMA projection GEMM ----------------
// z=0: r->HEADB, z=1: k->HEADB, z=2: v->VTB, z=3: g->GSILU
__global__ __launch_bounds__(256)
void gemm_bf4(const u16* __restrict__ xr, const u16* __restrict__ xk,
              const u16* __restrict__ xv, const u16* __restrict__ xg,
              const u16* __restrict__ WtR, const u16* __restrict__ WtK,
              const u16* __restrict__ WtV, const u16* __restrict__ WtG,
              u16* __restrict__ rbuf, u16* __restrict__ kbuf,
              u16* __restrict__ vT, float* __restrict__ gbuf) {
  __shared__ u16 As[128 * 32];
  __shared__ u16 Bs[64 * 32];
  int z = blockIdx.z;
  const u16* A = (z == 0) ? xr : (z == 1) ? xk : (z == 2) ? xv : xg;
  const u16* Bt = (z == 0) ? WtR : (z == 1) ? WtK : (z == 2) ? WtV : WtG;
  int m0 = blockIdx.y * 128, n0 = blockIdx.x * 64;
  int tid = threadIdx.x, w = tid >> 6, lane = tid & 63;
  int mq = w >> 1, nq = w & 1;
  f32x4 acc[4][2];
#pragma unroll
  for (int i = 0; i < 4; ++i)
#pragma unroll
    for (int j = 0; j < 2; ++j) acc[i][j] = {0.f, 0.f, 0.f, 0.f};
  for (int k0 = 0; k0 < 1024; k0 += 32) {
#pragma unroll
    for (int c2 = 0; c2 < 2; ++c2) {
      int ch = w * 2 + c2;
      int row = ch * 16 + (lane >> 2);
      gload16(A + (size_t)(m0 + row) * 1024 + k0 + (lane & 3) * 8, As + ch * 512);
    }
    {
      int row = w * 16 + (lane >> 2);
      gload16(Bt + (size_t)(n0 + row) * 1024 + k0 + (lane & 3) * 8, Bs + w * 512);
    }
    __syncthreads();
    short8 a[4], b[2];
#pragma unroll
    for (int mf = 0; mf < 4; ++mf)
      a[mf] = *(const short8*)(As + (mq * 64 + mf * 16 + (lane & 15)) * 32 + (lane >> 4) * 8);
#pragma unroll
    for (int nf = 0; nf < 2; ++nf)
      b[nf] = *(const short8*)(Bs + (nq * 32 + nf * 16 + (lane & 15)) * 32 + (lane >> 4) * 8);
#pragma unroll
    for (int mf = 0; mf < 4; ++mf)
#pragma unroll
      for (int nf = 0; nf < 2; ++nf) acc[mf][nf] = MFMA(a[mf], b[nf], acc[mf][nf]);
    __syncthreads();
  }
#pragma unroll
  for (int mf = 0; mf < 4; ++mf) {
#pragma unroll
    for (int nf = 0; nf < 2; ++nf) {
      int mb = m0 + mq * 64 + mf * 16 + (lane >> 4) * 4;
      int n = n0 + nq * 32 + nf * 16 + (lane & 15);
      if (z == 2) {  // VTB: vT[b*H+h][k][t] bf16
        u16 o[4];
#pragma unroll
        for (int r = 0; r < 4; ++r) o[r] = f2bf(acc[mf][nf][r]);
        int b2 = mb >> 10, t = mb & 1023;
        *(short4v*)(vT + (((size_t)(b2 * HH + (n >> 6))) * KK + (n & 63)) * TT + t) = *(short4v*)o;
      } else if (z == 3) {  // GSILU fp32 flat
#pragma unroll
        for (int r = 0; r < 4; ++r) {
          int m = mb + r;
          float v = acc[mf][nf][r];
          gbuf[(size_t)m * 1024 + n] = v / (1.f + __expf(-v));
        }
      } else {  // HEADB bf16 head layout
        u16* C = (z == 0) ? rbuf : kbuf;
#pragma unroll
        for (int r = 0; r < 4; ++r) {
          int m = mb + r;
          int b2 = m >> 10, t = m & 1023;
          C[(((size_t)(b2 * HH + (n >> 6))) * TT + t) * KK + (n & 63)] = f2bf(acc[mf][nf][r]);
        }
      }
    }
  }
}

// ---------------- bf16 MFMA GEMM (single, for W_o) ----------------
template <int EPI>
__global__ __launch_bounds__(256)
void gemm_bf(const u16* __restrict__ A, const u16* __restrict__ Bt,
             void* __restrict__ Cv) {
  __shared__ u16 As[128 * 32];
  __shared__ u16 Bs[64 * 32];
  int m0 = blockIdx.y * 128, n0 = blockIdx.x * 64;
  int tid = threadIdx.x, w = tid >> 6, lane = tid & 63;
  int mq = w >> 1, nq = w & 1;
  f32x4 acc[4][2];
#pragma unroll
  for (int i = 0; i < 4; ++i)
#pragma unroll
    for (int j = 0; j < 2; ++j) acc[i][j] = {0.f, 0.f, 0.f, 0.f};
  for (int k0 = 0; k0 < 1024; k0 += 32) {
#pragma unroll
    for (int c2 = 0; c2 < 2; ++c2) {
      int ch = w * 2 + c2;
      int row = ch * 16 + (lane >> 2);
      gload16(A + (size_t)(m0 + row) * 1024 + k0 + (lane & 3) * 8, As + ch * 512);
    }
    {
      int row = w * 16 + (lane >> 2);
      gload16(Bt + (size_t)(n0 + row) * 1024 + k0 + (lane & 3) * 8, Bs + w * 512);
    }
    __syncthreads();
    short8 a[4], b[2];
#pragma unroll
    for (int mf = 0; mf < 4; ++mf)
      a[mf] = *(const short8*)(As + (mq * 64 + mf * 16 + (lane & 15)) * 32 + (lane >> 4) * 8);
#pragma unroll
    for (int nf = 0; nf < 2; ++nf)
      b[nf] = *(const short8*)(Bs + (nq * 32 + nf * 16 + (lane & 15)) * 32 + (lane >> 4) * 8);
#pragma unroll
    for (int mf = 0; mf < 4; ++mf)
#pragma unroll
      for (int nf = 0; nf < 2; ++nf) acc[mf][nf] = MFMA(a[mf], b[nf], acc[mf][nf]);
    __syncthreads();
  }
#pragma unroll
  for (int mf = 0; mf < 4; ++mf) {
#pragma unroll
    for (int nf = 0; nf < 2; ++nf) {
      int mb = m0 + mq * 64 + mf * 16 + (lane >> 4) * 4;
      int n = n0 + nq * 32 + nf * 16 + (lane & 15);
#pragma unroll
      for (int r = 0; r < 4; ++r) {
        int m = mb + r;
        ((float*)Cv)[(size_t)m * 1024 + n] = acc[mf][nf][r];
      }
    }
  }
}

// ---------------- fp32 GEMM (K=64 LoRA-up paths) ----------------
template <int EPI>
__global__ __launch_bounds__(256)
void gemm_k(const float* __restrict__ A, const float* __restrict__ Bm,
            float* __restrict__ C, const float* __restrict__ bias, int N, int Kd) {
  __shared__ float As[16][132];
  __shared__ float Bs[16][68];
  int n0 = blockIdx.x * 64;
  int m0 = blockIdx.y * 128;
  int tid = threadIdx.x;
  int tx = tid & 15;
  int ty = tid >> 4;
  float acc[8][4] = {};
  for (int k0 = 0; k0 < Kd; k0 += 16) {
#pragma unroll
    for (int i = tid; i < 2048; i += 256) {
      int mm = i >> 4, kk2 = i & 15;
      As[kk2][mm] = A[(size_t)(m0 + mm) * Kd + (k0 + kk2)];
    }
#pragma unroll
    for (int i = tid; i < 1024; i += 256) {
      int kk2 = i >> 6, nn = i & 63;
      Bs[kk2][nn] = Bm[(size_t)(k0 + kk2) * N + (n0 + nn)];
    }
    __syncthreads();
#pragma unroll
    for (int kk2 = 0; kk2 < 16; ++kk2) {
      float a[8], b[4];
#pragma unroll
      for (int r = 0; r < 8; ++r) a[r] = As[kk2][ty * 8 + r];
#pragma unroll
      for (int c = 0; c < 4; ++c) b[c] = Bs[kk2][tx * 4 + c];
#pragma unroll
      for (int r = 0; r < 8; ++r)
#pragma unroll
        for (int c = 0; c < 4; ++c) acc[r][c] += a[r] * b[c];
    }
    __syncthreads();
  }
#pragma unroll
  for (int r = 0; r < 8; ++r) {
    int m = m0 + ty * 8 + r;
    int bb2 = m >> 10, t = m & 1023;
#pragma unroll
    for (int c = 0; c < 4; ++c) {
      int n = n0 + tx * 4 + c;
      float vv = acc[r][c];
      if constexpr (EPI == EPI_BIAS_HEAD) vv += bias[n];
      if constexpr (EPI == EPI_SIGBIAS_HEAD) vv = 1.f / (1.f + expf(-(vv + bias[n])));
      if constexpr (EPI == EPI_FLAT)
        C[(size_t)m * N + n] = vv;
      else
        C[(((size_t)(bb2 * HH + (n >> 6))) * TT + t) * KK + (n & 63)] = vv;
    }
  }
}

// ---------------- K4: kk normalize, kki, k scale (bf16 in/out) ----------------
__global__ __launch_bounds__(256)
void k4_kfix(u16* __restrict__ kbuf, u16* __restrict__ kkbuf, u16* __restrict__ kkibuf,
             const float* __restrict__ iclr, const float* __restrict__ k_k,
             const float* __restrict__ k_a) {
  int gid = blockIdx.x * 4 + (threadIdx.x >> 6);
  int lane = threadIdx.x & 63;
  size_t base = (size_t)gid * 64 + lane;
  int h = (gid >> 10) & (HH - 1);
  int d = h * 64 + lane;
  float kv = bf2f(kbuf[base]);
  float ic = iclr[base];
  float kkh = kv * k_k[d];
  float ss = kkh * kkh;
#pragma unroll
  for (int off = 32; off > 0; off >>= 1) ss += __shfl_xor(ss, off);
  float nrm = fmaxf(sqrtf(ss), 1e-12f);
  float kkv = kkh / nrm;
  kkbuf[base] = f2bf(kkv);
  kkibuf[base] = f2bf(kkv * ic);
  kbuf[base] = f2bf(kv * (1.f + (ic - 1.f) * k_a[d]));
}

// ---------------- K5: cumsum + clipped csf/csbs (fp32) ----------------
__global__ __launch_bounds__(1024)
void k5_cumsum(float* __restrict__ csf, float* __restrict__ csbs) {
  __shared__ float part[16][64];
  __shared__ float cs512s[64], wh512s[64];
  int bh = blockIdx.x;
  int lane = threadIdx.x & 63;
  int c = threadIdx.x >> 6;
  size_t base = (size_t)bh * TT * KK + (size_t)c * 64 * KK + lane;
  float p = 0.f;
  for (int i = 0; i < 64; ++i) {
    float wr = csf[base + (size_t)i * KK];
    float wh = -expf(wr);
    csbs[base + (size_t)i * KK] = wh;
    p += wh;
  }
  part[c][lane] = p;
  __syncthreads();
  if (threadIdx.x < 64) {
    float run = 0.f;
#pragma unroll
    for (int cc = 0; cc < 16; ++cc) {
      float tv = part[cc][lane];
      part[cc][lane] = run;
      run += tv;
    }
  }
  __syncthreads();
  float cs = part[c][lane];
  for (int i = 0; i < 64; ++i) {
    float wh = csbs[base + (size_t)i * KK];
    cs += wh;
    csbs[base + (size_t)i * KK] = cs;
    if (c == 8 && i == 0) { cs512s[lane] = cs; wh512s[lane] = wh; }
  }
  __syncthreads();
  float cs512 = cs512s[lane];
  float csb512 = cs512 - wh512s[lane];
  for (int i = 0; i < 64; ++i) {
    size_t g = base + (size_t)i * KK;
    float wr = csf[g];
    float wh = -expf(wr);
    float cc2 = csbs[g];
    csf[g] = fminf(fmaxf(cc2 - cs512, -60.f), 60.f);
    csbs[g] = fminf(fmaxf((cc2 - wh) - csb512, -60.f), 60.f);
  }
}

// ---------------- attention tile helpers (bf16 MFMA) ----------------
__device__ __forceinline__ void stage_copy(const u16* src, int rstride, u16* lds) {
  int tid = threadIdx.x;
#pragma unroll
  for (int c = 0; c < 2; ++c) {
    int ch = tid + c * 256;
    int row = ch >> 3, slot = ch & 7;
    short8 v = *(const short8*)(src + (size_t)row * rstride + slot * 8);
    *(short8*)((char*)lds + swzb(row, slot * 16)) = v;
  }
}
template <int PLUS>
__device__ __forceinline__ void stage_kexp(const u16* ksrc, const float* csrc, u16* lds) {
  int tid = threadIdx.x;
#pragma unroll
  for (int c = 0; c < 2; ++c) {
    int ch = tid + c * 256;
    int row = ch >> 3, slot = ch & 7;
    short8 kv = *(const short8*)(ksrc + (size_t)row * 64 + slot * 8);
    const float* cp = csrc + (size_t)row * 64 + slot * 8;
    u16 o[8];
#pragma unroll
    for (int j = 0; j < 8; ++j) {
      float cs = cp[j];
      o[j] = f2bf(bf2f((u16)kv[j]) * __expf(PLUS ? cs : -cs));
    }
    *(short8*)((char*)lds + swzb(row, slot * 16)) = *(short8*)o;
  }
}
template <int MASK>  // 0 none, 1 jl<il, 2 jl>il, 3 jl<=il
__device__ __forceinline__ void store_S(const f32x4 s[4], u16* St, int lane, int w) {
  int ig0 = w * 16 + (lane >> 4) * 4;
#pragma unroll
  for (int jf = 0; jf < 4; ++jf) {
    int jl = jf * 16 + (lane & 15);
#pragma unroll
    for (int r = 0; r < 4; ++r) {
      int il = ig0 + r;
      float v = s[jf][r];
      if (MASK == 1 && !(jl < il)) v = 0.f;
      if (MASK == 2 && !(jl > il)) v = 0.f;
      if (MASK == 3 && !(jl <= il)) v = 0.f;
      *(u16*)((char*)St + swzb(il, jl * 2)) = f2bf(v);
    }
  }
}
__device__ __forceinline__ void smm(const short8 afr[2], const u16* Kt, f32x4 s[4], int lane) {
#pragma unroll
  for (int jf = 0; jf < 4; ++jf) {
    f32x4 z = {0.f, 0.f, 0.f, 0.f};
#pragma unroll
    for (int ks = 0; ks < 2; ++ks) {
      short8 kb = *(const short8*)((const char*)Kt + swzb(jf * 16 + (lane & 15), ks * 64 + (lane >> 4) * 16));
      z = MFMA(afr[ks], kb, z);
    }
    s[jf] = z;
  }
}
__device__ __forceinline__ void pv(const u16* St, const u16* Vt, f32x4 acc[4], int lane, int w) {
#pragma unroll
  for (int ks = 0; ks < 2; ++ks) {
    short8 a = *(const short8*)((const char*)St + swzb(w * 16 + (lane & 15), ks * 64 + (lane >> 4) * 16));
#pragma unroll
    for (int cf = 0; cf < 4; ++cf) {
      short8 b = *(const short8*)((const char*)Vt + swzb(cf * 16 + (lane & 15), ks * 64 + (lane >> 4) * 16));
      acc[cf] = MFMA(a, b, acc[cf]);
    }
  }
}

// ---------------- K6: pass 1 ----------------
__global__ __launch_bounds__(256)
void k6_pass1(const u16* __restrict__ kk, const u16* __restrict__ kki,
              const u16* __restrict__ vT, u16* __restrict__ vfT, u16* __restrict__ vbT) {
  __shared__ u16 Kt[4096], Vt[4096], St[4096];
  int bh = blockIdx.y, it = blockIdx.x, i0 = it * 64;
  size_t hb = (size_t)bh * 65536;
  int tid = threadIdx.x, w = tid >> 6, lane = tid & 63;
  int iw = i0 + w * 16;
  short8 afr[2];
  {
    int row = iw + (lane & 15);
#pragma unroll
    for (int s = 0; s < 2; ++s)
      afr[s] = *(const short8*)(kki + hb + (size_t)row * 64 + s * 32 + (lane >> 4) * 8);
  }
  f32x4 af[4], ab[4];
#pragma unroll
  for (int c = 0; c < 4; ++c) { af[c] = {0.f, 0.f, 0.f, 0.f}; ab[c] = {0.f, 0.f, 0.f, 0.f}; }
  for (int jt = 0; jt < 16; ++jt) {
    int j0 = jt * 64;
    __syncthreads();
    stage_copy(kk + hb + (size_t)j0 * 64, 64, Kt);
    stage_copy(vT + hb + j0, 1024, Vt);
    __syncthreads();
    f32x4 s[4];
    smm(afr, Kt, s, lane);
    if (jt == it) {
      store_S<1>(s, St, lane, w);
      __syncthreads();
      pv(St, Vt, af, lane, w);
      __syncthreads();
      store_S<2>(s, St, lane, w);
      __syncthreads();
      pv(St, Vt, ab, lane, w);
    } else {
      store_S<0>(s, St, lane, w);
      __syncthreads();
      if (jt < it) pv(St, Vt, af, lane, w);
      else pv(St, Vt, ab, lane, w);
    }
  }
#pragma unroll
  for (int cf = 0; cf < 4; ++cf) {
    int c = cf * 16 + (lane & 15);
    int i = iw + (lane >> 4) * 4;
    size_t g = hb + (size_t)c * 1024 + i;
    short4v vv = *(const short4v*)(vT + g);
    u16 o1[4], o2[4];
#pragma unroll
    for (int r = 0; r < 4; ++r) {
      float v0 = bf2f((u16)vv[r]);
      o1[r] = f2bf(v0 - af[cf][r]);
      o2[r] = f2bf(v0 - ab[cf][r]);
    }
    *(short4v*)(vfT + g) = *(short4v*)o1;
    *(short4v*)(vbT + g) = *(short4v*)o2;
  }
}

// ---------------- K7: pass 2 ----------------
__global__ __launch_bounds__(256)
void k7_pass2(const u16* __restrict__ rb, const u16* __restrict__ kb,
              const float* __restrict__ csf, const float* __restrict__ csbs,
              const u16* __restrict__ vfT, const u16* __restrict__ vbT,
              float* __restrict__ y) {
  __shared__ u16 Kt[4096], Vt[4096], St[4096];
  int bh = blockIdx.y, it = blockIdx.x, i0 = it * 64;
  size_t hb = (size_t)bh * 65536;
  int tid = threadIdx.x, w = tid >> 6, lane = tid & 63;
  int iw = i0 + w * 16;
  short8 rf[2], rbk[2];
  {
    int row = iw + (lane & 15);
#pragma unroll
    for (int s = 0; s < 2; ++s) {
      int k = s * 32 + (lane >> 4) * 8;
      const u16* rp = rb + hb + (size_t)row * 64 + k;
      const float* cf = csf + hb + (size_t)row * 64 + k;
      const float* cb = csbs + hb + (size_t)row * 64 + k;
      u16 a[8], b[8];
#pragma unroll
      for (int j = 0; j < 8; ++j) {
        float rv = bf2f(rp[j]);
        a[j] = f2bf(rv * __expf(cf[j]));
        b[j] = f2bf(rv * __expf(-cb[j]));
      }
      rf[s] = *(short8*)a;
      rbk[s] = *(short8*)b;
    }
  }
  f32x4 acc[4];
#pragma unroll
  for (int c = 0; c < 4; ++c) acc[c] = {0.f, 0.f, 0.f, 0.f};
  for (int jt = 0; jt < 16; ++jt) {
    int j0 = jt * 64;
    if (jt <= it) {
      __syncthreads();
      stage_kexp<0>(kb + hb + (size_t)j0 * 64, csf + hb + (size_t)j0 * 64, Kt);
      stage_copy(vfT + hb + j0, 1024, Vt);
      __syncthreads();
      f32x4 s[4];
      smm(rf, Kt, s, lane);
      if (jt == it) store_S<3>(s, St, lane, w);
      else store_S<0>(s, St, lane, w);
      __syncthreads();
      pv(St, Vt, acc, lane, w);
    }
    if (jt >= it) {
      __syncthreads();
      stage_kexp<1>(kb + hb + (size_t)j0 * 64, csbs + hb + (size_t)j0 * 64, Kt);
      stage_copy(vbT + hb + j0, 1024, Vt);
      __syncthreads();
      f32x4 s[4];
      smm(rbk, Kt, s, lane);
      if (jt == it) store_S<2>(s, St, lane, w);
      else store_S<0>(s, St, lane, w);
      __syncthreads();
      pv(St, Vt, acc, lane, w);
    }
  }
#pragma unroll
  for (int cf = 0; cf < 4; ++cf) {
    int c = cf * 16 + (lane & 15);
#pragma unroll
    for (int r = 0; r < 4; ++r) {
      int i = iw + (lane >> 4) * 4 + r;
      y[hb + (size_t)i * 64 + c] = acc[cf][r];
    }
  }
}

// ---------------- K8: GroupNorm * ln + bias, * g -> bf16 ----------------
__global__ __launch_bounds__(256)
void k8_gnorm(const float* __restrict__ y, const float* __restrict__ g,
              const float* __restrict__ lnw, const float* __restrict__ lnb,
              u16* __restrict__ outb) {
  int bt = blockIdx.x;
  int b = bt >> 10, t = bt & 1023;
  int wv = threadIdx.x >> 6, lane = threadIdx.x & 63;
  for (int h = wv; h < HH; h += 4) {
    size_t idx = (((size_t)(b * HH + h)) * TT + t) * KK + lane;
    float v = y[idx];
    float s1 = v, s2 = v * v;
#pragma unroll
    for (int off = 32; off > 0; off >>= 1) {
      s1 += __shfl_xor(s1, off);
      s2 += __shfl_xor(s2, off);
    }
    float mu = s1 * (1.f / 64.f);
    float var = s2 * (1.f / 64.f) - mu * mu;
    float xn = (v - mu) * rsqrtf(var + 6.4e-4f);
    int d = h * 64 + lane;
    float o = xn * lnw[d] + lnb[d];
    outb[(size_t)bt * DD + d] = f2bf(o * g[(size_t)bt * DD + d]);
  }
}

extern "C" void kernel_launch(void* const* d_in, const int* in_sizes, int n_in,
                              void* d_out, int out_size, void* d_ws, size_t ws_size,
                              hipStream_t stream) {
  const float* x      = (const float*)d_in[0];
  const float* maa_x  = (const float*)d_in[1];
  const float* maa_w  = (const float*)d_in[2];
  const float* maa_k  = (const float*)d_in[3];
  const float* maa_v  = (const float*)d_in[4];
  const float* maa_r  = (const float*)d_in[5];
  const float* maa_g  = (const float*)d_in[6];
  const float* maa_a  = (const float*)d_in[7];
  const float* w1mix  = (const float*)d_in[8];
  const float* w2mix  = (const float*)d_in[9];
  const float* tdecay = (const float*)d_in[10];
  const float* wdec1  = (const float*)d_in[11];
  const float* wdec2  = (const float*)d_in[12];
  const float* a0     = (const float*)d_in[13];
  const float* a1     = (const float*)d_in[14];
  const float* a2     = (const float*)d_in[15];
  const float* k_k    = (const float*)d_in[16];
  const float* k_a    = (const float*)d_in[17];
  const float* W_r    = (const float*)d_in[18];
  const float* W_k    = (const float*)d_in[19];
  const float* W_v    = (const float*)d_in[20];
  const float* W_g    = (const float*)d_in[21];
  const float* W_o    = (const float*)d_in[22];
  const float* lnw    = (const float*)d_in[23];
  const float* lnb    = (const float*)d_in[24];
  float* out = (float*)d_out;

  const size_t NEf = NE;
  float* F = (float*)d_ws;
  float* xxx    = F;               // NE  (later reused as ybuf)
  float* ybuf   = F;
  float* xw     = F + 1 * NEf;
  float* xa     = F + 2 * NEf;
  float* csfb   = F + 3 * NEf;
  float* csbsb  = F + 4 * NEf;
  float* P3     = F + 3 * NEf;     // 8x2048x192 = 3145728 floats (inside csfb+csbsb; consumed before they're written)
  float* iclr   = F + 5 * NEf;
  float* gbuf   = F + 6 * NEf;
  float* hmix   = F + 7 * NEf;                 // 393216
  float* hdec   = F + 7 * NEf + 524288;        // 131072
  float* ha     = F + 7 * NEf + 786432;        // 131072
  float* Ppart  = F + 7 * NEf + 917504;        // 1048576 (8x2048x64)
  u16* U = (u16*)(F + 8 * NEf);
  u16* xr_b = U + 0 * NEf;
  u16* xk_b = U + 1 * NEf;
  u16* xv_b = U + 2 * NEf;
  u16* xg_b = U + 3 * NEf;
  u16* rbuf = U + 4 * NEf;
  u16* kbuf = U + 5 * NEf;
  u16* vT   = U + 6 * NEf;
  u16* kkb  = U + 7 * NEf;
  u16* kkib = U + 8 * NEf;
  u16* vfT  = U + 9 * NEf;
  u16* vbT  = U + 10 * NEf;
  u16* gnb  = U + 11 * NEf;
  u16* WtR  = U + 12 * NEf;
  u16* WtK  = U + 12 * NEf + 1048576;
  u16* WtV  = U + 12 * NEf + 2097152;
  u16* WtG  = U + 12 * NEf + 3145728;
  u16* WtO  = U + 12 * NEf + 4194304;

  dim3 blk(256);
  dim3 gT(16, 16);
  wtrans<<<gT, blk, 0, stream>>>(W_r, WtR);
  wtrans<<<gT, blk, 0, stream>>>(W_k, WtK);
  wtrans<<<gT, blk, 0, stream>>>(W_v, WtV);
  wtrans<<<gT, blk, 0, stream>>>(W_g, WtG);
  wtrans<<<gT, blk, 0, stream>>>(W_o, WtO);

  // xxx + hmix LoRA (split-K)
  k1_xxx<<<NBT, blk, 0, stream>>>(x, maa_x, xxx);
  skinny_gemm<<<dim3(64, 8, 3), blk, 0, stream>>>(xxx, w1mix, P3, 192);
  reduce8<1><<<1536, blk, 0, stream>>>(P3, hmix, 393216);

  k2_mix6<<<dim3(4, NBT / 8), blk, 0, stream>>>(x, hmix, w2mix, maa_w, maa_k,
                                                maa_v, maa_r, maa_g, maa_a,
                                                xw, xa, xk_b, xv_b, xr_b, xg_b);

  // 4 projections in one fused dispatch (4 blocks/CU)
  gemm_bf4<<<dim3(16, 16, 4), blk, 0, stream>>>(xr_b, xk_b, xv_b, xg_b,
                                                WtR, WtK, WtV, WtG,
                                                rbuf, kbuf, vT, gbuf);

  // skinny LoRA-down paths (split-K, fp32)
  skinny_gemm<<<dim3(64, 8, 1), blk, 0, stream>>>(xw, wdec1, Ppart, 64);
  reduce8<1><<<512, blk, 0, stream>>>(Ppart, hdec, 131072);
  skinny_gemm<<<dim3(64, 8, 1), blk, 0, stream>>>(xa, a1, Ppart, 64);
  reduce8<0><<<512, blk, 0, stream>>>(Ppart, ha, 131072);

  gemm_k<EPI_BIAS_HEAD><<<gT, blk, 0, stream>>>(hdec, wdec2, csfb, tdecay, 1024, 64);
  gemm_k<EPI_SIGBIAS_HEAD><<<gT, blk, 0, stream>>>(ha, a2, iclr, a0, 1024, 64);

  k4_kfix<<<(BB * HH * TT) / 4, blk, 0, stream>>>(kbuf, kkb, kkib, iclr, k_k, k_a);
  k5_cumsum<<<BB * HH, 1024, 0, stream>>>(csfb, csbsb);
  k6_pass1<<<dim3(16, BB * HH), blk, 0, stream>>>(kkb, kkib, vT, vfT, vbT);
  k7_pass2<<<dim3(16, BB * HH), blk, 0, stream>>>(rbuf, kbuf, csfb, csbsb, vfT, vbT, ybuf);
  k8_gnorm<<<NBT, blk, 0, stream>>>(ybuf, gbuf, lnw, lnb, gnb);
  gemm_bf<EPI_OUT><<<gT, blk, 0, stream>>>(gnb, WtO, out);
}

// Round 5
// 310.775 us; speedup vs baseline: 6.9821x; 1.0242x over previous
//
#include <hip/hip_runtime.h>
#include <math.h>

#define BB 2
#define TT 1024
#define DD 1024
#define HH 16
#define KK 64
#define NBT 2048              // B*T
#define NE  2097152ULL        // B*T*D

typedef unsigned short u16;
typedef __attribute__((ext_vector_type(8))) short short8;   // 8 bf16 (4 VGPR)
typedef __attribute__((ext_vector_type(4))) short short4v;  // 4 bf16 (8B)
typedef __attribute__((ext_vector_type(4))) float f32x4;

__device__ __forceinline__ float bf2f(u16 u) {
  union { unsigned int i; float f; } v; v.i = ((unsigned int)u) << 16; return v.f;
}
__device__ __forceinline__ u16 f2bf(float x) {
  union { float f; unsigned int u; } v; v.f = x;
  unsigned int r = v.u + 0x7fffu + ((v.u >> 16) & 1u);
  return (u16)(r >> 16);
}
__device__ __forceinline__ f32x4 MFMA(short8 a, short8 b, f32x4 c) {
  return __builtin_amdgcn_mfma_f32_16x16x32_bf16(a, b, c, 0, 0, 0);
}
// XOR swizzle for [64 rows][128B] LDS tiles (G4: 128B rows are 32-way conflict)
__device__ __forceinline__ int swzb(int row, int kbyte) {
  return row * 128 + (kbyte ^ ((row & 7) << 4));
}
__device__ __forceinline__ void gload16(const void* g, void* l) {
  __builtin_amdgcn_global_load_lds((const __attribute__((address_space(1))) void*)g,
                                   (__attribute__((address_space(3))) void*)l, 16, 0, 0);
}

constexpr int EPI_FLAT = 0, EPI_BIAS_HEAD = 4, EPI_SIGBIAS_HEAD = 5;
constexpr int EPI_OUT = 0;

// ---------------- K1a: xxx = x + dx * maa_x (elementwise) ----------------
__global__ __launch_bounds__(256)
void k1_xxx(const float* __restrict__ x, const float* __restrict__ maa_x,
            float* __restrict__ xxx) {
  int row = blockIdx.x;
  int t = row & (TT - 1);
  int d0 = threadIdx.x * 4;
  size_t g = (size_t)row * DD + d0;
  f32x4 xc = *(const f32x4*)(x + g);
  f32x4 xl = {0.f, 0.f, 0.f, 0.f}, xr = {0.f, 0.f, 0.f, 0.f};
  if (t != 0) xl = *(const f32x4*)(x + g - DD);
  if (t != TT - 1) xr = *(const f32x4*)(x + g + DD);
  f32x4 mx = *(const f32x4*)(maa_x + d0);
  f32x4 o;
#pragma unroll
  for (int j = 0; j < 4; ++j)
    o[j] = xc[j] + (0.5f * (xl[j] + xr[j]) - xc[j]) * mx[j];
  *(f32x4*)(xxx + g) = o;
}

// ---------------- skinny split-K fp32 GEMM ----------------
__global__ __launch_bounds__(256)
void skinny_gemm(const float* __restrict__ A, const float* __restrict__ B,
                 float* __restrict__ P, int N) {
  __shared__ float As[32][129];
  __shared__ float Bs[128][64];
  int m0 = blockIdx.x * 32;
  int kb = blockIdx.y;      // 0..7
  int n0 = blockIdx.z * 64; // N tiles
  int tid = threadIdx.x;
  for (int i = tid; i < 1024; i += 256) {
    int r = i >> 5, c4 = (i & 31) * 4;
    f32x4 v = *(const f32x4*)(A + (size_t)(m0 + r) * 1024 + kb * 128 + c4);
    As[r][c4 + 0] = v[0]; As[r][c4 + 1] = v[1];
    As[r][c4 + 2] = v[2]; As[r][c4 + 3] = v[3];
  }
  for (int i = tid; i < 2048; i += 256) {
    int r = i >> 4, c4 = (i & 15) * 4;
    f32x4 v = *(const f32x4*)(B + (size_t)(kb * 128 + r) * N + n0 + c4);
    Bs[r][c4 + 0] = v[0]; Bs[r][c4 + 1] = v[1];
    Bs[r][c4 + 2] = v[2]; Bs[r][c4 + 3] = v[3];
  }
  __syncthreads();
  int col = tid & 63, rg = tid >> 6;  // 4 waves: 8 rows each
  float acc[8] = {};
  for (int k = 0; k < 128; ++k) {
    float b = Bs[k][col];
#pragma unroll
    for (int r = 0; r < 8; ++r) acc[r] += As[rg * 8 + r][k] * b;
  }
#pragma unroll
  for (int r = 0; r < 8; ++r)
    P[((size_t)kb * NBT + m0 + rg * 8 + r) * N + n0 + col] = acc[r];
}

// ---------------- reduce 8 partials ----------------
template <int TANH>
__global__ __launch_bounds__(256)
void reduce8(const float* __restrict__ P, float* __restrict__ C, int total) {
  size_t i = (size_t)blockIdx.x * 256 + threadIdx.x;
  float s = 0.f;
#pragma unroll
  for (int kb = 0; kb < 8; ++kb) s += P[(size_t)kb * total + i];
  C[i] = TANH ? tanhf(s) : s;
}

// ---------------- K2: six mixed inputs ----------------
__global__ __launch_bounds__(256)
void k2_mix6(const float* __restrict__ x, const float* __restrict__ hmix,
             const float* __restrict__ W2,
             const float* __restrict__ maa_w, const float* __restrict__ maa_k,
             const float* __restrict__ maa_v, const float* __restrict__ maa_r,
             const float* __restrict__ maa_g, const float* __restrict__ maa_a,
             float* __restrict__ xw, float* __restrict__ xa,
             u16* __restrict__ xk_b, u16* __restrict__ xv_b,
             u16* __restrict__ xr_b, u16* __restrict__ xg_b) {
  __shared__ float hs[8][192];
  int row0 = blockIdx.y * 8;
  int d = blockIdx.x * 256 + threadIdx.x;
  for (int i = threadIdx.x; i < 8 * 192; i += 256)
    hs[i / 192][i % 192] = hmix[(size_t)row0 * 192 + i];
  __syncthreads();
  float xv_[8], dx_[8];
#pragma unroll
  for (int r = 0; r < 8; ++r) {
    int row = row0 + r;
    int t = row & (TT - 1);
    size_t g = (size_t)row * DD + d;
    float xc = x[g];
    float xl = (t == 0) ? 0.f : x[g - DD];
    float xr2 = (t == TT - 1) ? 0.f : x[g + DD];
    xv_[r] = xc;
    dx_[r] = 0.5f * (xl + xr2) - xc;
  }
  const float* maas[6] = {maa_w, maa_k, maa_v, maa_r, maa_g, maa_a};
#pragma unroll
  for (int s = 0; s < 6; ++s) {
    float acc[8] = {0, 0, 0, 0, 0, 0, 0, 0};
    for (int m = 0; m < 32; ++m) {
      float w = W2[(size_t)(s * 32 + m) * DD + d];
#pragma unroll
      for (int r = 0; r < 8; ++r) acc[r] += hs[r][s * 32 + m] * w;
    }
    float ma = maas[s][d];
#pragma unroll
    for (int r = 0; r < 8; ++r) {
      size_t idx = (size_t)(row0 + r) * DD + d;
      float val = xv_[r] + dx_[r] * (ma + acc[r]);
      if (s == 0) xw[idx] = val;
      else if (s == 5) xa[idx] = val;
      else if (s == 1) xk_b[idx] = f2bf(val);
      else if (s == 2) xv_b[idx] = f2bf(val);
      else if (s == 3) xr_b[idx] = f2bf(val);
      else xg_b[idx] = f2bf(val);
    }
  }
}

// ---------------- weight transpose fp32[k][n] -> bf16 [n][k] ----------------
__global__ __launch_bounds__(256)
void wtrans(const float* __restrict__ W, u16* __restrict__ Wt) {
  __shared__ float tl[64][65];
  int k0 = blockIdx.x * 64, n0 = blockIdx.y * 64;
  int tid = threadIdx.x;
  int r = tid >> 2, c0 = (tid & 3) * 16;
#pragma unroll
  for (int j = 0; j < 16; j += 4) {
    f32x4 v = *(const f32x4*)(W + (size_t)(k0 + r) * 1024 + n0 + c0 + j);
    tl[r][c0 + j + 0] = v[0]; tl[r][c0 + j + 1] = v[1];
    tl[r][c0 + j + 2] = v[2]; tl[r][c0 + j + 3] = v[3];
  }
  __syncthreads();
  u16 o[16];
#pragma unroll
  for (int j = 0; j < 16; ++j) o[j] = f2bf(tl[c0 + j][r]);
  *(short8*)(Wt + (size_t)(n0 + r) * 1024 + k0 + c0) = *(short8*)(o);
  *(short8*)(Wt + (size_t)(n0 + r) * 1024 + k0 + c0 + 8) = *(short8*)(o + 8);
}

// ---------------- fused 4-way bf16 MFMA projection GEMM ----------------
__global__ __launch_bounds__(256)
void gemm_bf4(const u16* __restrict__ xr, const u16* __restrict__ xk,
              const u16* __restrict__ xv, const u16* __restrict__ xg,
              const u16* __restrict__ WtR, const u16* __restrict__ WtK,
              const u16* __restrict__ WtV, const u16* __restrict__ WtG,
              u16* __restrict__ rbuf, u16* __restrict__ kbuf,
              u16* __restrict__ vT, float* __restrict__ gbuf) {
  __shared__ u16 As[128 * 32];
  __shared__ u16 Bs[64 * 32];
  int z = blockIdx.z;
  const u16* A = (z == 0) ? xr : (z == 1) ? xk : (z == 2) ? xv : xg;
  const u16* Bt = (z == 0) ? WtR : (z == 1) ? WtK : (z == 2) ? WtV : WtG;
  int m0 = blockIdx.y * 128, n0 = blockIdx.x * 64;
  int tid = threadIdx.x, w = tid >> 6, lane = tid & 63;
  int mq = w >> 1, nq = w & 1;
  f32x4 acc[4][2];
#pragma unroll
  for (int i = 0; i < 4; ++i)
#pragma unroll
    for (int j = 0; j < 2; ++j) acc[i][j] = {0.f, 0.f, 0.f, 0.f};
  for (int k0 = 0; k0 < 1024; k0 += 32) {
#pragma unroll
    for (int c2 = 0; c2 < 2; ++c2) {
      int ch = w * 2 + c2;
      int row = ch * 16 + (lane >> 2);
      gload16(A + (size_t)(m0 + row) * 1024 + k0 + (lane & 3) * 8, As + ch * 512);
    }
    {
      int row = w * 16 + (lane >> 2);
      gload16(Bt + (size_t)(n0 + row) * 1024 + k0 + (lane & 3) * 8, Bs + w * 512);
    }
    __syncthreads();
    short8 a[4], b[2];
#pragma unroll
    for (int mf = 0; mf < 4; ++mf)
      a[mf] = *(const short8*)(As + (mq * 64 + mf * 16 + (lane & 15)) * 32 + (lane >> 4) * 8);
#pragma unroll
    for (int nf = 0; nf < 2; ++nf)
      b[nf] = *(const short8*)(Bs + (nq * 32 + nf * 16 + (lane & 15)) * 32 + (lane >> 4) * 8);
#pragma unroll
    for (int mf = 0; mf < 4; ++mf)
#pragma unroll
      for (int nf = 0; nf < 2; ++nf) acc[mf][nf] = MFMA(a[mf], b[nf], acc[mf][nf]);
    __syncthreads();
  }
#pragma unroll
  for (int mf = 0; mf < 4; ++mf) {
#pragma unroll
    for (int nf = 0; nf < 2; ++nf) {
      int mb = m0 + mq * 64 + mf * 16 + (lane >> 4) * 4;
      int n = n0 + nq * 32 + nf * 16 + (lane & 15);
      if (z == 2) {  // VTB: vT[b*H+h][k][t] bf16
        u16 o[4];
#pragma unroll
        for (int r = 0; r < 4; ++r) o[r] = f2bf(acc[mf][nf][r]);
        int b2 = mb >> 10, t = mb & 1023;
        *(short4v*)(vT + (((size_t)(b2 * HH + (n >> 6))) * KK + (n & 63)) * TT + t) = *(short4v*)o;
      } else if (z == 3) {  // GSILU fp32 flat
#pragma unroll
        for (int r = 0; r < 4; ++r) {
          int m = mb + r;
          float v = acc[mf][nf][r];
          gbuf[(size_t)m * 1024 + n] = v / (1.f + __expf(-v));
        }
      } else {  // HEADB bf16 head layout
        u16* C = (z == 0) ? rbuf : kbuf;
#pragma unroll
        for (int r = 0; r < 4; ++r) {
          int m = mb + r;
          int b2 = m >> 10, t = m & 1023;
          C[(((size_t)(b2 * HH + (n >> 6))) * TT + t) * KK + (n & 63)] = f2bf(acc[mf][nf][r]);
        }
      }
    }
  }
}

// ---------------- bf16 MFMA GEMM (single, for W_o) ----------------
template <int EPI>
__global__ __launch_bounds__(256)
void gemm_bf(const u16* __restrict__ A, const u16* __restrict__ Bt,
             void* __restrict__ Cv) {
  __shared__ u16 As[128 * 32];
  __shared__ u16 Bs[64 * 32];
  int m0 = blockIdx.y * 128, n0 = blockIdx.x * 64;
  int tid = threadIdx.x, w = tid >> 6, lane = tid & 63;
  int mq = w >> 1, nq = w & 1;
  f32x4 acc[4][2];
#pragma unroll
  for (int i = 0; i < 4; ++i)
#pragma unroll
    for (int j = 0; j < 2; ++j) acc[i][j] = {0.f, 0.f, 0.f, 0.f};
  for (int k0 = 0; k0 < 1024; k0 += 32) {
#pragma unroll
    for (int c2 = 0; c2 < 2; ++c2) {
      int ch = w * 2 + c2;
      int row = ch * 16 + (lane >> 2);
      gload16(A + (size_t)(m0 + row) * 1024 + k0 + (lane & 3) * 8, As + ch * 512);
    }
    {
      int row = w * 16 + (lane >> 2);
      gload16(Bt + (size_t)(n0 + row) * 1024 + k0 + (lane & 3) * 8, Bs + w * 512);
    }
    __syncthreads();
    short8 a[4], b[2];
#pragma unroll
    for (int mf = 0; mf < 4; ++mf)
      a[mf] = *(const short8*)(As + (mq * 64 + mf * 16 + (lane & 15)) * 32 + (lane >> 4) * 8);
#pragma unroll
    for (int nf = 0; nf < 2; ++nf)
      b[nf] = *(const short8*)(Bs + (nq * 32 + nf * 16 + (lane & 15)) * 32 + (lane >> 4) * 8);
#pragma unroll
    for (int mf = 0; mf < 4; ++mf)
#pragma unroll
      for (int nf = 0; nf < 2; ++nf) acc[mf][nf] = MFMA(a[mf], b[nf], acc[mf][nf]);
    __syncthreads();
  }
#pragma unroll
  for (int mf = 0; mf < 4; ++mf) {
#pragma unroll
    for (int nf = 0; nf < 2; ++nf) {
      int mb = m0 + mq * 64 + mf * 16 + (lane >> 4) * 4;
      int n = n0 + nq * 32 + nf * 16 + (lane & 15);
#pragma unroll
      for (int r = 0; r < 4; ++r) {
        int m = mb + r;
        ((float*)Cv)[(size_t)m * 1024 + n] = acc[mf][nf][r];
      }
    }
  }
}

// ---------------- fp32 GEMM (K=64 LoRA-up paths) ----------------
template <int EPI>
__global__ __launch_bounds__(256)
void gemm_k(const float* __restrict__ A, const float* __restrict__ Bm,
            float* __restrict__ C, const float* __restrict__ bias, int N, int Kd) {
  __shared__ float As[16][132];
  __shared__ float Bs[16][68];
  int n0 = blockIdx.x * 64;
  int m0 = blockIdx.y * 128;
  int tid = threadIdx.x;
  int tx = tid & 15;
  int ty = tid >> 4;
  float acc[8][4] = {};
  for (int k0 = 0; k0 < Kd; k0 += 16) {
#pragma unroll
    for (int i = tid; i < 2048; i += 256) {
      int mm = i >> 4, kk2 = i & 15;
      As[kk2][mm] = A[(size_t)(m0 + mm) * Kd + (k0 + kk2)];
    }
#pragma unroll
    for (int i = tid; i < 1024; i += 256) {
      int kk2 = i >> 6, nn = i & 63;
      Bs[kk2][nn] = Bm[(size_t)(k0 + kk2) * N + (n0 + nn)];
    }
    __syncthreads();
#pragma unroll
    for (int kk2 = 0; kk2 < 16; ++kk2) {
      float a[8], b[4];
#pragma unroll
      for (int r = 0; r < 8; ++r) a[r] = As[kk2][ty * 8 + r];
#pragma unroll
      for (int c = 0; c < 4; ++c) b[c] = Bs[kk2][tx * 4 + c];
#pragma unroll
      for (int r = 0; r < 8; ++r)
#pragma unroll
        for (int c = 0; c < 4; ++c) acc[r][c] += a[r] * b[c];
    }
    __syncthreads();
  }
#pragma unroll
  for (int r = 0; r < 8; ++r) {
    int m = m0 + ty * 8 + r;
    int bb2 = m >> 10, t = m & 1023;
#pragma unroll
    for (int c = 0; c < 4; ++c) {
      int n = n0 + tx * 4 + c;
      float vv = acc[r][c];
      if constexpr (EPI == EPI_BIAS_HEAD) vv += bias[n];
      if constexpr (EPI == EPI_SIGBIAS_HEAD) vv = 1.f / (1.f + expf(-(vv + bias[n])));
      if constexpr (EPI == EPI_FLAT)
        C[(size_t)m * N + n] = vv;
      else
        C[(((size_t)(bb2 * HH + (n >> 6))) * TT + t) * KK + (n & 63)] = vv;
    }
  }
}

// ---------------- K4: kk normalize, kki, k scale ----------------
__global__ __launch_bounds__(256)
void k4_kfix(u16* __restrict__ kbuf, u16* __restrict__ kkbuf, u16* __restrict__ kkibuf,
             const float* __restrict__ iclr, const float* __restrict__ k_k,
             const float* __restrict__ k_a) {
  int gid = blockIdx.x * 4 + (threadIdx.x >> 6);
  int lane = threadIdx.x & 63;
  size_t base = (size_t)gid * 64 + lane;
  int h = (gid >> 10) & (HH - 1);
  int d = h * 64 + lane;
  float kv = bf2f(kbuf[base]);
  float ic = iclr[base];
  float kkh = kv * k_k[d];
  float ss = kkh * kkh;
#pragma unroll
  for (int off = 32; off > 0; off >>= 1) ss += __shfl_xor(ss, off);
  float nrm = fmaxf(sqrtf(ss), 1e-12f);
  float kkv = kkh / nrm;
  kkbuf[base] = f2bf(kkv);
  kkibuf[base] = f2bf(kkv * ic);
  kbuf[base] = f2bf(kv * (1.f + (ic - 1.f) * k_a[d]));
}

// ---------------- K5: cumsum + clipped csf/csbs (fp32) ----------------
__global__ __launch_bounds__(1024)
void k5_cumsum(float* __restrict__ csf, float* __restrict__ csbs) {
  __shared__ float part[16][64];
  __shared__ float cs512s[64], wh512s[64];
  int bh = blockIdx.x;
  int lane = threadIdx.x & 63;
  int c = threadIdx.x >> 6;
  size_t base = (size_t)bh * TT * KK + (size_t)c * 64 * KK + lane;
  float p = 0.f;
  for (int i = 0; i < 64; ++i) {
    float wr = csf[base + (size_t)i * KK];
    float wh = -expf(wr);
    csbs[base + (size_t)i * KK] = wh;
    p += wh;
  }
  part[c][lane] = p;
  __syncthreads();
  if (threadIdx.x < 64) {
    float run = 0.f;
#pragma unroll
    for (int cc = 0; cc < 16; ++cc) {
      float tv = part[cc][lane];
      part[cc][lane] = run;
      run += tv;
    }
  }
  __syncthreads();
  float cs = part[c][lane];
  for (int i = 0; i < 64; ++i) {
    float wh = csbs[base + (size_t)i * KK];
    cs += wh;
    csbs[base + (size_t)i * KK] = cs;
    if (c == 8 && i == 0) { cs512s[lane] = cs; wh512s[lane] = wh; }
  }
  __syncthreads();
  float cs512 = cs512s[lane];
  float csb512 = cs512 - wh512s[lane];
  for (int i = 0; i < 64; ++i) {
    size_t g = base + (size_t)i * KK;
    float wr = csf[g];
    float wh = -expf(wr);
    float cc2 = csbs[g];
    csf[g] = fminf(fmaxf(cc2 - cs512, -60.f), 60.f);
    csbs[g] = fminf(fmaxf((cc2 - wh) - csb512, -60.f), 60.f);
  }
}

// ---------------- K5b: factored operands (bit-identical to old in-loop exp) ----------------
__global__ __launch_bounds__(256)
void k5b_factor(const u16* __restrict__ rb, const u16* __restrict__ kb,
                const float* __restrict__ csf, const float* __restrict__ csbs,
                u16* __restrict__ rfb, u16* __restrict__ rbb,
                u16* __restrict__ kfb, u16* __restrict__ kbw) {
  size_t i0 = ((size_t)blockIdx.x * 256 + threadIdx.x) * 8;
  short8 rv = *(const short8*)(rb + i0);
  short8 kv = *(const short8*)(kb + i0);
  float cfa[8], cba[8];
  *(f32x4*)&cfa[0] = *(const f32x4*)(csf + i0);
  *(f32x4*)&cfa[4] = *(const f32x4*)(csf + i0 + 4);
  *(f32x4*)&cba[0] = *(const f32x4*)(csbs + i0);
  *(f32x4*)&cba[4] = *(const f32x4*)(csbs + i0 + 4);
  u16 orf[8], orb2[8], okf[8], okb[8];
#pragma unroll
  for (int j = 0; j < 8; ++j) {
    float rvf = bf2f((u16)rv[j]), kvf = bf2f((u16)kv[j]);
    orf[j]  = f2bf(rvf * __expf(cfa[j]));
    okf[j]  = f2bf(kvf * __expf(-cfa[j]));
    orb2[j] = f2bf(rvf * __expf(-cba[j]));
    okb[j]  = f2bf(kvf * __expf(cba[j]));
  }
  *(short8*)(rfb + i0) = *(short8*)orf;
  *(short8*)(rbb + i0) = *(short8*)orb2;
  *(short8*)(kfb + i0) = *(short8*)okf;
  *(short8*)(kbw + i0) = *(short8*)okb;
}

// ---------------- attention tile helpers (bf16 MFMA) ----------------
struct SReg { short8 a0, a1, b0, b1; };
template <int RSA, int RSB>
__device__ __forceinline__ void sload(const u16* ka, const u16* vb, SReg& r) {
  int t0 = threadIdx.x, t1 = threadIdx.x + 256;
  r.a0 = *(const short8*)(ka + (size_t)(t0 >> 3) * RSA + (t0 & 7) * 8);
  r.a1 = *(const short8*)(ka + (size_t)(t1 >> 3) * RSA + (t1 & 7) * 8);
  r.b0 = *(const short8*)(vb + (size_t)(t0 >> 3) * RSB + (t0 & 7) * 8);
  r.b1 = *(const short8*)(vb + (size_t)(t1 >> 3) * RSB + (t1 & 7) * 8);
}
__device__ __forceinline__ void swrite(u16* Kt, u16* Vt, const SReg& r) {
  int t0 = threadIdx.x, t1 = threadIdx.x + 256;
  *(short8*)((char*)Kt + swzb(t0 >> 3, (t0 & 7) * 16)) = r.a0;
  *(short8*)((char*)Kt + swzb(t1 >> 3, (t1 & 7) * 16)) = r.a1;
  *(short8*)((char*)Vt + swzb(t0 >> 3, (t0 & 7) * 16)) = r.b0;
  *(short8*)((char*)Vt + swzb(t1 >> 3, (t1 & 7) * 16)) = r.b1;
}
template <int MASK>  // 0 none, 1 jl<il, 2 jl>il, 3 jl<=il
__device__ __forceinline__ void store_S(const f32x4 s[4], u16* St, int lane, int w) {
  int ig0 = w * 16 + (lane >> 4) * 4;
#pragma unroll
  for (int jf = 0; jf < 4; ++jf) {
    int jl = jf * 16 + (lane & 15);
#pragma unroll
    for (int r = 0; r < 4; ++r) {
      int il = ig0 + r;
      float v = s[jf][r];
      if (MASK == 1 && !(jl < il)) v = 0.f;
      if (MASK == 2 && !(jl > il)) v = 0.f;
      if (MASK == 3 && !(jl <= il)) v = 0.f;
      *(u16*)((char*)St + swzb(il, jl * 2)) = f2bf(v);
    }
  }
}
__device__ __forceinline__ void smm(short8 a0, short8 a1, const u16* Kt, f32x4 s[4], int lane) {
#pragma unroll
  for (int jf = 0; jf < 4; ++jf) {
    f32x4 z = {0.f, 0.f, 0.f, 0.f};
    short8 kb0 = *(const short8*)((const char*)Kt + swzb(jf * 16 + (lane & 15), (lane >> 4) * 16));
    z = MFMA(a0, kb0, z);
    short8 kb1 = *(const short8*)((const char*)Kt + swzb(jf * 16 + (lane & 15), 64 + (lane >> 4) * 16));
    z = MFMA(a1, kb1, z);
    s[jf] = z;
  }
}
__device__ __forceinline__ void pv(const u16* St, const u16* Vt, f32x4 acc[4], int lane, int w) {
#pragma unroll
  for (int ks = 0; ks < 2; ++ks) {
    short8 a = *(const short8*)((const char*)St + swzb(w * 16 + (lane & 15), ks * 64 + (lane >> 4) * 16));
#pragma unroll
    for (int cf = 0; cf < 4; ++cf) {
      short8 b = *(const short8*)((const char*)Vt + swzb(cf * 16 + (lane & 15), ks * 64 + (lane >> 4) * 16));
      acc[cf] = MFMA(a, b, acc[cf]);
    }
  }
}

// ---------------- K6: pass 1 (1 barrier/phase, dbuf, XCD-swizzled 1D grid) ----------------
__global__ __launch_bounds__(256)
void k6_pass1(const u16* __restrict__ kk, const u16* __restrict__ kki,
              const u16* __restrict__ vT, u16* __restrict__ vfT, u16* __restrict__ vbT) {
  __shared__ u16 Kt[2][4096], Vt[2][4096], St[4096];
  int wg = blockIdx.x;
  int bh = wg & 31, it = wg >> 5, i0 = it * 64;
  size_t hb = (size_t)bh * 65536;
  int tid = threadIdx.x, w = tid >> 6, lane = tid & 63;
  int iw = i0 + w * 16;
  int row = iw + (lane & 15), ko = (lane >> 4) * 8;
  short8 a0 = *(const short8*)(kki + hb + (size_t)row * 64 + ko);
  short8 a1 = *(const short8*)(kki + hb + (size_t)row * 64 + 32 + ko);
  f32x4 af[4], ab[4];
#pragma unroll
  for (int c = 0; c < 4; ++c) { af[c] = {0.f, 0.f, 0.f, 0.f}; ab[c] = {0.f, 0.f, 0.f, 0.f}; }
  SReg sr, nx;
  sload<64, 1024>(kk + hb, vT + hb, sr);
  swrite(Kt[0], Vt[0], sr);
  __syncthreads();
  for (int s = 0; s < 16; ++s) {
    int cur = s & 1;
    if (s < 15)
      sload<64, 1024>(kk + hb + (size_t)(s + 1) * 4096, vT + hb + (s + 1) * 64, nx);
    f32x4 sv[4];
    smm(a0, a1, Kt[cur], sv, lane);
    if (s == it) {
      store_S<1>(sv, St, lane, w);
      pv(St, Vt[cur], af, lane, w);
      store_S<2>(sv, St, lane, w);
      pv(St, Vt[cur], ab, lane, w);
    } else if (s < it) {
      store_S<0>(sv, St, lane, w);
      pv(St, Vt[cur], af, lane, w);
    } else {
      store_S<0>(sv, St, lane, w);
      pv(St, Vt[cur], ab, lane, w);
    }
    if (s < 15) swrite(Kt[cur ^ 1], Vt[cur ^ 1], nx);
    __syncthreads();
  }
#pragma unroll
  for (int cf = 0; cf < 4; ++cf) {
    int c = cf * 16 + (lane & 15);
    int i = iw + (lane >> 4) * 4;
    size_t g = hb + (size_t)c * 1024 + i;
    short4v vv = *(const short4v*)(vT + g);
    u16 o1[4], o2[4];
#pragma unroll
    for (int r = 0; r < 4; ++r) {
      float v0 = bf2f((u16)vv[r]);
      o1[r] = f2bf(v0 - af[cf][r]);
      o2[r] = f2bf(v0 - ab[cf][r]);
    }
    *(short4v*)(vfT + g) = *(short4v*)o1;
    *(short4v*)(vbT + g) = *(short4v*)o2;
  }
}

// ---------------- K7: pass 2 (precomputed factors, 1 barrier/phase, dbuf) ----------------
__global__ __launch_bounds__(256)
void k7_pass2(const u16* __restrict__ rfb, const u16* __restrict__ rbb,
              const u16* __restrict__ kfb, const u16* __restrict__ kbw,
              const u16* __restrict__ vfT, const u16* __restrict__ vbT,
              float* __restrict__ y) {
  __shared__ u16 Kt[2][4096], Vt[2][4096], St[4096];
  int wg = blockIdx.x;
  int bh = wg & 31, it = wg >> 5, i0 = it * 64;
  size_t hb = (size_t)bh * 65536;
  int tid = threadIdx.x, w = tid >> 6, lane = tid & 63;
  int iw = i0 + w * 16;
  int row = iw + (lane & 15), ko = (lane >> 4) * 8;
  short8 rf0 = *(const short8*)(rfb + hb + (size_t)row * 64 + ko);
  short8 rf1 = *(const short8*)(rfb + hb + (size_t)row * 64 + 32 + ko);
  short8 rb0 = *(const short8*)(rbb + hb + (size_t)row * 64 + ko);
  short8 rb1 = *(const short8*)(rbb + hb + (size_t)row * 64 + 32 + ko);
  f32x4 acc[4];
#pragma unroll
  for (int c = 0; c < 4; ++c) acc[c] = {0.f, 0.f, 0.f, 0.f};
  SReg sr, nx;
  {
    // phase 0 is always forward jt=0
    sload<64, 1024>(kfb + hb, vfT + hb, sr);
    swrite(Kt[0], Vt[0], sr);
  }
  __syncthreads();
  for (int s = 0; s < 17; ++s) {
    int cur = s & 1;
    if (s < 16) {
      int s1 = s + 1;
      bool f1 = (s1 <= it);
      int j1 = f1 ? s1 : s1 - 1;
      const u16* kp = (f1 ? kfb : kbw) + hb + (size_t)j1 * 4096;
      const u16* vp = (f1 ? vfT : vbT) + hb + j1 * 64;
      sload<64, 1024>(kp, vp, nx);
    }
    bool fwd = (s <= it);
    int jt = fwd ? s : s - 1;
    short8 a0 = fwd ? rf0 : rb0;
    short8 a1 = fwd ? rf1 : rb1;
    f32x4 sv[4];
    smm(a0, a1, Kt[cur], sv, lane);
    if (jt == it) {
      if (fwd) store_S<3>(sv, St, lane, w);
      else store_S<2>(sv, St, lane, w);
    } else {
      store_S<0>(sv, St, lane, w);
    }
    pv(St, Vt[cur], acc, lane, w);
    if (s < 16) swrite(Kt[cur ^ 1], Vt[cur ^ 1], nx);
    __syncthreads();
  }
#pragma unroll
  for (int cf = 0; cf < 4; ++cf) {
    int c = cf * 16 + (lane & 15);
#pragma unroll
    for (int r = 0; r < 4; ++r) {
      int i = iw + (lane >> 4) * 4 + r;
      y[hb + (size_t)i * 64 + c] = acc[cf][r];
    }
  }
}

// ---------------- K8: GroupNorm * ln + bias, * g -> bf16 ----------------
__global__ __launch_bounds__(256)
void k8_gnorm(const float* __restrict__ y, const float* __restrict__ g,
              const float* __restrict__ lnw, const float* __restrict__ lnb,
              u16* __restrict__ outb) {
  int bt = blockIdx.x;
  int b = bt >> 10, t = bt & 1023;
  int wv = threadIdx.x >> 6, lane = threadIdx.x & 63;
  for (int h = wv; h < HH; h += 4) {
    size_t idx = (((size_t)(b * HH + h)) * TT + t) * KK + lane;
    float v = y[idx];
    float s1 = v, s2 = v * v;
#pragma unroll
    for (int off = 32; off > 0; off >>= 1) {
      s1 += __shfl_xor(s1, off);
      s2 += __shfl_xor(s2, off);
    }
    float mu = s1 * (1.f / 64.f);
    float var = s2 * (1.f / 64.f) - mu * mu;
    float xn = (v - mu) * rsqrtf(var + 6.4e-4f);
    int d = h * 64 + lane;
    float o = xn * lnw[d] + lnb[d];
    outb[(size_t)bt * DD + d] = f2bf(o * g[(size_t)bt * DD + d]);
  }
}

extern "C" void kernel_launch(void* const* d_in, const int* in_sizes, int n_in,
                              void* d_out, int out_size, void* d_ws, size_t ws_size,
                              hipStream_t stream) {
  const float* x      = (const float*)d_in[0];
  const float* maa_x  = (const float*)d_in[1];
  const float* maa_w  = (const float*)d_in[2];
  const float* maa_k  = (const float*)d_in[3];
  const float* maa_v  = (const float*)d_in[4];
  const float* maa_r  = (const float*)d_in[5];
  const float* maa_g  = (const float*)d_in[6];
  const float* maa_a  = (const float*)d_in[7];
  const float* w1mix  = (const float*)d_in[8];
  const float* w2mix  = (const float*)d_in[9];
  const float* tdecay = (const float*)d_in[10];
  const float* wdec1  = (const float*)d_in[11];
  const float* wdec2  = (const float*)d_in[12];
  const float* a0     = (const float*)d_in[13];
  const float* a1     = (const float*)d_in[14];
  const float* a2     = (const float*)d_in[15];
  const float* k_k    = (const float*)d_in[16];
  const float* k_a    = (const float*)d_in[17];
  const float* W_r    = (const float*)d_in[18];
  const float* W_k    = (const float*)d_in[19];
  const float* W_v    = (const float*)d_in[20];
  const float* W_g    = (const float*)d_in[21];
  const float* W_o    = (const float*)d_in[22];
  const float* lnw    = (const float*)d_in[23];
  const float* lnb    = (const float*)d_in[24];
  float* out = (float*)d_out;

  const size_t NEf = NE;
  float* F = (float*)d_ws;
  float* xxx    = F;               // NE  (later reused as ybuf)
  float* ybuf   = F;
  float* xw     = F + 1 * NEf;     // later reused: rfb/rbb (bf16)
  float* xa     = F + 2 * NEf;     // later reused: kfb/kbw (bf16)
  float* csfb   = F + 3 * NEf;
  float* csbsb  = F + 4 * NEf;
  float* P3     = F + 3 * NEf;     // 8x2048x192 floats (consumed before csfb/csbsb written)
  float* iclr   = F + 5 * NEf;
  float* gbuf   = F + 6 * NEf;
  float* hmix   = F + 7 * NEf;                 // 393216
  float* hdec   = F + 7 * NEf + 524288;        // 131072
  float* ha     = F + 7 * NEf + 786432;        // 131072
  float* Ppart  = F + 7 * NEf + 917504;        // 1048576 (8x2048x64)
  u16* rfb = (u16*)xw;             // after xw consumed by skinny_gemm
  u16* rbb = rfb + NEf;
  u16* kfb = (u16*)xa;             // after xa consumed by skinny_gemm
  u16* kbw = kfb + NEf;
  u16* U = (u16*)(F + 8 * NEf);
  u16* xr_b = U + 0 * NEf;
  u16* xk_b = U + 1 * NEf;
  u16* xv_b = U + 2 * NEf;
  u16* xg_b = U + 3 * NEf;
  u16* rbuf = U + 4 * NEf;
  u16* kbuf = U + 5 * NEf;
  u16* vT   = U + 6 * NEf;
  u16* kkb  = U + 7 * NEf;
  u16* kkib = U + 8 * NEf;
  u16* vfT  = U + 9 * NEf;
  u16* vbT  = U + 10 * NEf;
  u16* gnb  = U + 11 * NEf;
  u16* WtR  = U + 12 * NEf;
  u16* WtK  = U + 12 * NEf + 1048576;
  u16* WtV  = U + 12 * NEf + 2097152;
  u16* WtG  = U + 12 * NEf + 3145728;
  u16* WtO  = U + 12 * NEf + 4194304;

  dim3 blk(256);
  dim3 gT(16, 16);
  wtrans<<<gT, blk, 0, stream>>>(W_r, WtR);
  wtrans<<<gT, blk, 0, stream>>>(W_k, WtK);
  wtrans<<<gT, blk, 0, stream>>>(W_v, WtV);
  wtrans<<<gT, blk, 0, stream>>>(W_g, WtG);
  wtrans<<<gT, blk, 0, stream>>>(W_o, WtO);

  // xxx + hmix LoRA (split-K)
  k1_xxx<<<NBT, blk, 0, stream>>>(x, maa_x, xxx);
  skinny_gemm<<<dim3(64, 8, 3), blk, 0, stream>>>(xxx, w1mix, P3, 192);
  reduce8<1><<<1536, blk, 0, stream>>>(P3, hmix, 393216);

  k2_mix6<<<dim3(4, NBT / 8), blk, 0, stream>>>(x, hmix, w2mix, maa_w, maa_k,
                                                maa_v, maa_r, maa_g, maa_a,
                                                xw, xa, xk_b, xv_b, xr_b, xg_b);

  // 4 projections in one fused dispatch
  gemm_bf4<<<dim3(16, 16, 4), blk, 0, stream>>>(xr_b, xk_b, xv_b, xg_b,
                                                WtR, WtK, WtV, WtG,
                                                rbuf, kbuf, vT, gbuf);

  // skinny LoRA-down paths (split-K, fp32)
  skinny_gemm<<<dim3(64, 8, 1), blk, 0, stream>>>(xw, wdec1, Ppart, 64);
  reduce8<1><<<512, blk, 0, stream>>>(Ppart, hdec, 131072);
  skinny_gemm<<<dim3(64, 8, 1), blk, 0, stream>>>(xa, a1, Ppart, 64);
  reduce8<0><<<512, blk, 0, stream>>>(Ppart, ha, 131072);

  gemm_k<EPI_BIAS_HEAD><<<gT, blk, 0, stream>>>(hdec, wdec2, csfb, tdecay, 1024, 64);
  gemm_k<EPI_SIGBIAS_HEAD><<<gT, blk, 0, stream>>>(ha, a2, iclr, a0, 1024, 64);

  k4_kfix<<<(BB * HH * TT) / 4, blk, 0, stream>>>(kbuf, kkb, kkib, iclr, k_k, k_a);
  k5_cumsum<<<BB * HH, 1024, 0, stream>>>(csfb, csbsb);
  k5b_factor<<<1024, blk, 0, stream>>>(rbuf, kbuf, csfb, csbsb, rfb, rbb, kfb, kbw);
  k6_pass1<<<512, blk, 0, stream>>>(kkb, kkib, vT, vfT, vbT);
  k7_pass2<<<512, blk, 0, stream>>>(rfb, rbb, kfb, kbw, vfT, vbT, ybuf);
  k8_gnorm<<<NBT, blk, 0, stream>>>(ybuf, gbuf, lnw, lnb, gnb);
  gemm_bf<EPI_OUT><<<gT, blk, 0, stream>>>(gnb, WtO, out);
}